// Round 4
// baseline (538.147 us; speedup 1.0000x reference)
//
#include <hip/hip_runtime.h>
#include <hip/hip_bf16.h>

typedef __bf16 bf16;
typedef __bf16 bf16x8 __attribute__((ext_vector_type(8)));
typedef float floatx4 __attribute__((ext_vector_type(4)));

#define B_    8
#define N_    4096
#define C_    512
#define BN_   32768      // B_*N_
#define HID_  2048
#define SCALE_ 0.125f    // 64^-0.5

// async 16B global -> LDS (m97 lever)
__device__ __forceinline__ void load_lds16(const void* g, void* l) {
    __builtin_amdgcn_global_load_lds(
        (const __attribute__((address_space(1))) void*)g,
        (__attribute__((address_space(3))) void*)l, 16, 0, 0);
}

// fast exact-tanh GELU: v * sigmoid(1.5957691*(v+0.044715 v^3))
__device__ __forceinline__ float gelu_fast(float v) {
    float c = fmaf(v * v, 0.044715f, 1.0f) * v;
    float e = __builtin_amdgcn_exp2f(-2.3022082f * c);
    return v * __builtin_amdgcn_rcpf(1.0f + e);
}

// ====================== dtype sniff ========================================
__global__ void sniff_kernel(const unsigned int* __restrict__ xw, int* __restrict__ flag)
{
    int t = threadIdx.x;
    int votes = 0;
#pragma unroll
    for (int i = 0; i < 4; i++) {
        unsigned w = xw[t * 4 + i];
        if (w == 0u) continue;
        unsigned a = w & 0xFFFFu;
        unsigned e = (a >> 7) & 0xFFu;
        if (a != 0u && e >= 110u && e <= 135u) votes++; else votes--;
    }
#pragma unroll
    for (int off = 32; off; off >>= 1) votes += __shfl_xor(votes, off);
    __shared__ int s[4];
    if ((t & 63) == 0) s[t >> 6] = votes;
    __syncthreads();
    if (t == 0) *flag = (s[0] + s[1] + s[2] + s[3]) > 0 ? 1 : 0;  // 1 = bf16
}

// ====================== param conversion ===================================
struct ConvArgs {
    const void* src[12];
    unsigned    dstoff[12];
    int         n[12];
};

__global__ __launch_bounds__(256) void convert_params(
    ConvArgs args, char* __restrict__ ws, const int* __restrict__ flag)
{
    int seg = blockIdx.y;
    int n = args.n[seg];
    int base = blockIdx.x * 2048;
    if (base >= n) return;
    bf16* dst = (bf16*)(ws + args.dstoff[seg]);
    const void* src = args.src[seg];
    bool isbf = (*flag != 0);
#pragma unroll
    for (int j = 0; j < 8; j++) {
        int idx = base + threadIdx.x + j * 256;
        if (idx < n) {
            float v = isbf ? (float)((const bf16*)src)[idx]
                           : ((const float*)src)[idx];
            dst[idx] = (bf16)v;
        }
    }
}

// ====================== LayerNorm variants =================================
__device__ __forceinline__ void ln_core(float f[8], const bf16* w, const bf16* b,
                                        int lane, bf16* outp)
{
    float s = 0.f, sq = 0.f;
#pragma unroll
    for (int j = 0; j < 8; j++) { s += f[j]; sq += f[j]*f[j]; }
#pragma unroll
    for (int off = 32; off; off >>= 1) { s += __shfl_xor(s, off); sq += __shfl_xor(sq, off); }
    float mean = s * (1.f/512.f);
    float var  = sq * (1.f/512.f) - mean*mean;
    float inv  = rsqrtf(var + 1e-5f);
    bf16x8 wv = *(const bf16x8*)(w + lane*8);
    bf16x8 bv = *(const bf16x8*)(b + lane*8);
    bf16x8 o;
#pragma unroll
    for (int j = 0; j < 8; j++) o[j] = (bf16)((f[j]-mean)*inv*(float)wv[j] + (float)bv[j]);
    *(bf16x8*)outp = o;
}

__global__ __launch_bounds__(256) void ln_dyn_kernel(
    const void* __restrict__ xv, const bf16* __restrict__ w,
    const bf16* __restrict__ b, bf16* __restrict__ out, const int* __restrict__ flag)
{
    int wave = threadIdx.x >> 6, lane = threadIdx.x & 63;
    size_t row = (size_t)blockIdx.x * 4 + wave;
    float f[8];
    if (*flag) {
        bf16x8 v = *(const bf16x8*)((const bf16*)xv + row * C_ + lane * 8);
#pragma unroll
        for (int j = 0; j < 8; j++) f[j] = (float)v[j];
    } else {
        const float4* p = (const float4*)((const float*)xv + row * C_ + lane * 8);
        float4 v0 = p[0], v1 = p[1];
        f[0]=v0.x; f[1]=v0.y; f[2]=v0.z; f[3]=v0.w;
        f[4]=v1.x; f[5]=v1.y; f[6]=v1.z; f[7]=v1.w;
    }
    ln_core(f, w, b, lane, out + row * C_ + lane*8);
}

__global__ __launch_bounds__(256) void ln_b16_kernel(
    const bf16* __restrict__ x, const bf16* __restrict__ w,
    const bf16* __restrict__ b, bf16* __restrict__ out)
{
    int wave = threadIdx.x >> 6, lane = threadIdx.x & 63;
    size_t row = (size_t)blockIdx.x * 4 + wave;
    bf16x8 v = *(const bf16x8*)(x + row * C_ + lane * 8);
    float f[8];
#pragma unroll
    for (int j = 0; j < 8; j++) f[j] = (float)v[j];
    ln_core(f, w, b, lane, out + row * C_ + lane*8);
}

__global__ __launch_bounds__(256) void ln_f32_kernel(
    const float* __restrict__ x, const bf16* __restrict__ w,
    const bf16* __restrict__ b, bf16* __restrict__ out)
{
    int wave = threadIdx.x >> 6, lane = threadIdx.x & 63;
    size_t row = (size_t)blockIdx.x * 4 + wave;
    const float4* p = (const float4*)(x + row * C_ + lane * 8);
    float4 v0 = p[0], v1 = p[1];
    float f[8] = { v0.x, v0.y, v0.z, v0.w, v1.x, v1.y, v1.z, v1.w };
    ln_core(f, w, b, lane, out + row * C_ + lane*8);
}

// ====================== 256x256 pipelined MFMA GEMM (persistent) ===========
// R3 post-mortem: MfmaUtil 27.5% == MFMA_floor/observed (2483/7630 cyc per
// K-tile). The {reads; bar; lgkm0; MFMA; bar} phase serializes the LDS pipe
// (1536 cyc/K-tile) with the matrix pipe (2483) + 8 barriers. Fix here:
// ONE-PHASE-AHEAD register pipelining, 1 barrier/phase:
//   phase p: { stage; [q3: vmcnt(4)]; barrier; issue ds_reads for p+1;
//              MFMA(p) from regs loaded at p-1 }
// -> LDS serves p+1's reads concurrently with MFMA(p). Reads/K-tile: q0=8
// (bf0 JIT + bf1), q1=8 (afO), q2=0, q3=8 (afE' next K-tile). bf0 is
// single-buffered (JIT at q0, lifetime q0..q3) to keep unified regs <256
// (acc 128 AGPR + ~96 frag VGPR). Hazards re-verified:
//  RAW: every early read covered by the vmcnt(4) chain; q3's next-K-tile
//    reads sit AFTER vmcnt(4)+barrier (cross-wave staging visibility).
//  WAR: same-phase stage slot disjoint from read slots (all 4 phases);
//    slot overwrite >= 2 phases after last read; skew < 1 phase via barrier.
// Stage map & vmcnt(4)@q3 proof unchanged from R2/R3 (12 outstanding -> 4
// leaves exactly {A0(t+2),B0(t+2)} in flight; K-tile t+1 fully resident).
enum { EPI_NONE = 0, EPI_BIAS = 1, EPI_BIAS_RESID = 2, EPI_BIAS_GELU = 3, EPI_QKV = 4 };

// LDS layout: global (row, col8) lives at row*64 + (col8 ^ ((row&7)<<3)) [G4]
#define RD_A(dst, S, H)                                                        \
    _Pragma("unroll") for (int mi = 0; mi < 4; mi++) {                         \
        int row = wm * 64 + mi * 16 + l16;                                     \
        _Pragma("unroll") for (int ks = 0; ks < 2; ks++)                       \
            dst[mi][ks] = *(const bf16x8*)(&Asl[S][H][0][0] + row * 64 +       \
                ((ks * 32 + quad * 8) ^ ((row & 7) << 3)));                    \
    }
#define RD_B(dst, S, H)                                                        \
    _Pragma("unroll") for (int ni = 0; ni < 2; ni++) {                         \
        int row = wn * 32 + ni * 16 + l16;                                     \
        _Pragma("unroll") for (int ks = 0; ks < 2; ks++)                       \
            dst[ni][ks] = *(const bf16x8*)(&Bsl[S][H][0][0] + row * 64 +       \
                ((ks * 32 + quad * 8) ^ ((row & 7) << 3)));                    \
    }
#define MM(AF, BF, AH, BH)                                                     \
    __builtin_amdgcn_s_setprio(1);                                             \
    _Pragma("unroll") for (int mi = 0; mi < 4; mi++)                           \
    _Pragma("unroll") for (int ni = 0; ni < 2; ni++)                           \
    _Pragma("unroll") for (int ks = 0; ks < 2; ks++)                           \
        acc[(AH)*4+mi][(BH)*2+ni] = __builtin_amdgcn_mfma_f32_16x16x32_bf16(   \
            AF[mi][ks], BF[ni][ks], acc[(AH)*4+mi][(BH)*2+ni], 0, 0, 0);       \
    __builtin_amdgcn_s_setprio(0);
#define STAGE2(GB, LB)                                                         \
    { load_lds16((GB) + goff0, (LB) + loff0);                                  \
      load_lds16((GB) + goff1, (LB) + loff1); }

template<typename OutT, int EPI>
__global__ __launch_bounds__(512, 2) void gemm256(
    const bf16* __restrict__ A, const bf16* __restrict__ W,
    const bf16* __restrict__ bias, const void* __restrict__ resid,
    const int* __restrict__ flag,
    OutT* __restrict__ Cout, bf16* __restrict__ Cout2, int M, int Nn, int K)
{
    __shared__ bf16 Asl[2][2][128][64];   // [slot][half][row][k]  64 KiB
    __shared__ bf16 Bsl[2][2][128][64];   // 64 KiB
    const int t = threadIdx.x;
    const int wv = t >> 6, lane = t & 63;
    const int quad = lane >> 4, l16 = lane & 15;
    const int wm = wv >> 2, wn = wv & 3;          // wave tile: 128 rows x 64 cols
    const int Nt = Nn >> 8;
    const int total = (M >> 8) * Nt;
    const int G = gridDim.x;
    const int NKT = K >> 6;                        // BK=64 K-tiles (even)

    // loop-invariant stage addressing (16B chunk c: row=c>>3, swizzled slot)
    const int c0 = t, c1 = 512 + t;
    const int r0 = c0 >> 3, r1 = c1 >> 3;
    const size_t goff0 = (size_t)r0 * K + (size_t)(((c0 & 7) ^ (r0 & 7)) * 8);
    const size_t goff1 = (size_t)r1 * K + (size_t)(((c1 & 7) ^ (r1 & 7)) * 8);
    const int loff0 = c0 * 8, loff1 = c1 * 8;

    int id = blockIdx.x;
    if (id >= total) return;
    int m0 = (((id >> 3) / Nt) * 8 + (id & 7)) * 256;
    int n0 = ((id >> 3) % Nt) * 256;

    // ---- prologue: tile-0 K-tile 0 fully + first halves of K-tile 1 ----
    STAGE2(A + (size_t)m0 * K,         &Asl[0][0][0][0]);  // A0(0)
    STAGE2(W + (size_t)n0 * K,         &Bsl[0][0][0][0]);  // B0(0)
    STAGE2(A + (size_t)(m0 + 128) * K, &Asl[0][1][0][0]);  // A1(0)
    STAGE2(W + (size_t)n0 * K + 64,    &Bsl[1][0][0][0]);  // B0(1)
    STAGE2(W + (size_t)(n0 + 128) * K, &Bsl[0][1][0][0]);  // B1(0)
    STAGE2(A + (size_t)m0 * K + 64,    &Asl[1][0][0][0]);  // A0(1)
    asm volatile("s_waitcnt vmcnt(4)");   // K-tile 0 + B0(1) path resident enough
    __builtin_amdgcn_s_barrier();

    bf16x8 afE[4][2], afO[4][2], bf0[2][2], bf1[2][2];
    RD_A(afE, 0, 0)                       // A0(0) for q0 of kt=0

    for (;;) {
        const int idn = id + G;
        const bool hn = idn < total;
        int m0n = 0, n0n = 0;
        if (hn) {
            m0n = (((idn >> 3) / Nt) * 8 + (idn & 7)) * 256;
            n0n = ((idn >> 3) % Nt) * 256;
        }

        floatx4 acc[8][4] = {};

        for (int kt = 0; kt < NKT; ++kt) {
            const int s = kt & 1;
            // ---- q0: MFMA(afE,bf0[JIT]); reads bf0,bf1; stage A1(next) ----
            {
                const bf16* p = (kt + 1 < NKT)
                    ? A + (size_t)(m0 + 128) * K + (size_t)(kt + 1) * 64
                    : (hn ? A + (size_t)(m0n + 128) * K : nullptr);
                if (p) STAGE2(p, &Asl[s ^ 1][1][0][0]);
            }
            __builtin_amdgcn_s_barrier();
            RD_B(bf0, s, 0)
            RD_B(bf1, s, 1)
            __builtin_amdgcn_sched_barrier(0);
            MM(afE, bf0, 0, 0)
            // ---- q1: MFMA(afE,bf1); reads afO; stage B1(next) ----
            {
                const bf16* p = (kt + 1 < NKT)
                    ? W + (size_t)(n0 + 128) * K + (size_t)(kt + 1) * 64
                    : (hn ? W + (size_t)(n0n + 128) * K : nullptr);
                if (p) STAGE2(p, &Bsl[s ^ 1][1][0][0]);
            }
            __builtin_amdgcn_s_barrier();
            RD_A(afO, s, 1)
            __builtin_amdgcn_sched_barrier(0);
            MM(afE, bf1, 0, 1)
            // ---- q2: MFMA(afO,bf1); no reads; stage A0(next-next) ----
            {
                const bf16* p = (kt + 2 < NKT)
                    ? A + (size_t)m0 * K + (size_t)(kt + 2) * 64
                    : (hn ? A + (size_t)m0n * K + (size_t)(kt + 2 - NKT) * 64 : nullptr);
                if (p) STAGE2(p, &Asl[s][0][0][0]);
            }
            __builtin_amdgcn_s_barrier();
            MM(afO, bf1, 1, 1)
            // ---- q3: stage B0(next-next); vmcnt; reads afE'(next); MFMA ----
            {
                const bf16* p = (kt + 2 < NKT)
                    ? W + (size_t)n0 * K + (size_t)(kt + 2) * 64
                    : (hn ? W + (size_t)n0n * K + (size_t)(kt + 2 - NKT) * 64 : nullptr);
                if (p) STAGE2(p, &Bsl[s][0][0][0]);
            }
            if (kt + 1 < NKT || hn) {
                if (kt + 2 < NKT || hn) asm volatile("s_waitcnt vmcnt(4)");
                else                    asm volatile("s_waitcnt vmcnt(0)");
            }
            __builtin_amdgcn_s_barrier();
            if (kt + 1 < NKT || hn) { RD_A(afE, s ^ 1, 0) }
            __builtin_amdgcn_sched_barrier(0);
            MM(afO, bf0, 1, 0)
        }

        // ---- epilogue (next tile's K-tile 0 resident; afE preloaded) ----
        size_t ldc = (size_t)Nn; int csub = 0; bool to2 = false;
        if (EPI == EPI_QKV) {
            if (n0 >= 512) { to2 = true; ldc = 1024; csub = 512; }
            else           { ldc = 512; }
        }
        bool isbf = false;
        if (EPI == EPI_BIAS_RESID) isbf = (*flag != 0);

#pragma unroll
        for (int mg = 0; mg < 8; mg++) {
            int rowg = m0 + (mg >> 2) * 128 + wm * 64 + (mg & 3) * 16 + quad * 4;
#pragma unroll
            for (int ng = 0; ng < 4; ng++) {
                int col = n0 + (ng >> 1) * 128 + wn * 32 + (ng & 1) * 16 + l16;
                float bv = (EPI == EPI_BIAS || EPI == EPI_BIAS_RESID || EPI == EPI_BIAS_GELU)
                           ? (float)bias[col] : 0.f;
#pragma unroll
                for (int r = 0; r < 4; r++) {
                    size_t idx = (size_t)(rowg + r) * ldc + (col - csub);
                    float v = acc[mg][ng][r] + bv;
                    if (EPI == EPI_BIAS_RESID) {
                        float rres = isbf ? (float)((const bf16*)resid)[idx]
                                          : ((const float*)resid)[idx];
                        v += rres;
                    }
                    if (EPI == EPI_BIAS_GELU)  v = gelu_fast(v);
                    if (EPI == EPI_QKV && to2) Cout2[idx] = (bf16)v;
                    else                       Cout[idx]  = (OutT)v;
                }
            }
        }

        if (!hn) break;
        id = idn; m0 = m0n; n0 = n0n;
    }
}

// ====================== attention (MFMA) ===================================
// grid (8 slices, 64 bh): partial[(bh*8+s)*4096 + d*64+e] over 512 tokens
__global__ __launch_bounds__(256) void attn_logits_mfma(
    const bf16* __restrict__ kv, float* __restrict__ partial)
{
    __shared__ bf16 Kt[64][136];
    __shared__ bf16 Vt[64][136];
    int s = blockIdx.x, bh = blockIdx.y, b = bh >> 3, h = bh & 7;
    int t = threadIdx.x, wave = t >> 6, lane = t & 63;
    int quad = lane >> 4, l16 = lane & 15;
    floatx4 acc[4] = {};
    for (int c = 0; c < 4; c++) {
        int n0 = s * 512 + c * 128;
        {
            int isv = t >> 7;
            int r   = t & 127;
            const bf16* gp = &kv[((size_t)b * N_ + n0 + r) * 1024 + h * 64 + isv * 512];
            bf16x8 rowv[8];
#pragma unroll
            for (int u = 0; u < 8; u++) rowv[u] = *(const bf16x8*)(gp + u * 8);
            bf16 (*dst)[136] = isv ? Vt : Kt;
#pragma unroll
            for (int u = 0; u < 8; u++)
#pragma unroll
                for (int jj = 0; jj < 8; jj++)
                    dst[u * 8 + jj][r] = rowv[u][jj];
        }
        __syncthreads();
#pragma unroll
        for (int ks = 0; ks < 4; ks++) {
            bf16x8 af = *(const bf16x8*)&Kt[wave * 16 + l16][ks * 32 + quad * 8];
#pragma unroll
            for (int ni = 0; ni < 4; ni++) {
                bf16x8 bfv = *(const bf16x8*)&Vt[ni * 16 + l16][ks * 32 + quad * 8];
                acc[ni] = __builtin_amdgcn_mfma_f32_16x16x32_bf16(af, bfv, acc[ni], 0, 0, 0);
            }
        }
        __syncthreads();
    }
    float* p = partial + ((size_t)bh * 8 + s) * 4096;
#pragma unroll
    for (int ni = 0; ni < 4; ni++)
#pragma unroll
        for (int r = 0; r < 4; r++)
            p[(wave * 16 + quad * 4 + r) * 64 + ni * 16 + l16] = acc[ni][r];
}

// softmax: grid (4, 64); block handles 16 d rows (wave*4 + r)
__global__ __launch_bounds__(256) void attn_softmax_kernel(
    const float* __restrict__ partial, bf16* __restrict__ attnb)
{
    int bh = blockIdx.y;
    int wave = threadIdx.x >> 6, lane = threadIdx.x & 63;
    for (int r = 0; r < 4; r++) {
        int d = blockIdx.x * 16 + wave * 4 + r;
        float v = 0.f;
#pragma unroll
        for (int s = 0; s < 8; s++) v += partial[((size_t)bh*8 + s)*4096 + d*64 + lane];
        v *= SCALE_;
        float m = v;
#pragma unroll
        for (int off = 32; off; off >>= 1) m = fmaxf(m, __shfl_xor(m, off));
        float p = expf(v - m);
        float sum = p;
#pragma unroll
        for (int off = 32; off; off >>= 1) sum += __shfl_xor(sum, off);
        attnb[(size_t)bh*4096 + d*64 + lane] = (bf16)(p / sum);
    }
}

// apply: outT[n][h*64+d] = sum_e attn[d][e] * q[n][h*64+e]
__global__ __launch_bounds__(256) void attn_apply_mfma(
    const bf16* __restrict__ q, const bf16* __restrict__ attnb,
    bf16* __restrict__ outT)
{
    int bh = blockIdx.y, b = bh >> 3, h = bh & 7;
    int t = threadIdx.x, wave = t >> 6, lane = t & 63;
    int quad = lane >> 4, l16 = lane & 15;
    int nbase = blockIdx.x * 256 + wave * 64;
    bf16x8 bfrag[4][2];
#pragma unroll
    for (int di = 0; di < 4; di++)
#pragma unroll
        for (int ks = 0; ks < 2; ks++)
            bfrag[di][ks] = *(const bf16x8*)&attnb[(size_t)bh*4096 + (di*16 + l16)*64 + ks*32 + quad*8];
    floatx4 acc[4][4] = {};
#pragma unroll
    for (int mi = 0; mi < 4; mi++) {
#pragma unroll
        for (int ks = 0; ks < 2; ks++) {
            bf16x8 af = *(const bf16x8*)&q[((size_t)b*N_ + nbase + mi*16 + l16)*512 + h*64 + ks*32 + quad*8];
#pragma unroll
            for (int di = 0; di < 4; di++)
                acc[mi][di] = __builtin_amdgcn_mfma_f32_16x16x32_bf16(af, bfrag[di][ks], acc[mi][di], 0, 0, 0);
        }
    }
#pragma unroll
    for (int mi = 0; mi < 4; mi++)
#pragma unroll
        for (int di = 0; di < 4; di++)
#pragma unroll
            for (int r = 0; r < 4; r++)
                outT[((size_t)b*N_ + nbase + mi*16 + quad*4 + r)*512 + h*64 + di*16 + l16] =
                    (bf16)acc[mi][di][r];
}

// ====================== ECA ================================================
__global__ __launch_bounds__(256) void pooled_kernel(
    const bf16* __restrict__ y, float* __restrict__ pooled)
{
    int bc = blockIdx.x;
    const bf16* p = y + (size_t)bc * 4096 + threadIdx.x * 16;
    float s = 0.f;
#pragma unroll
    for (int i = 0; i < 2; i++) {
        bf16x8 v = *(const bf16x8*)(p + i*8);
#pragma unroll
        for (int j = 0; j < 8; j++) s += (float)v[j];
    }
#pragma unroll
    for (int off = 32; off; off >>= 1) s += __shfl_xor(s, off);
    __shared__ float red[4];
    if ((threadIdx.x & 63) == 0) red[threadIdx.x >> 6] = s;
    __syncthreads();
    if (threadIdx.x == 0)
        pooled[bc] = (red[0] + red[1] + red[2] + red[3]) * (1.f/4096.f);
}

__global__ void gate_kernel(const float* __restrict__ pooled,
                            const bf16* __restrict__ eca_w, float* __restrict__ gate1)
{
    int c = threadIdx.x, b = blockIdx.x;
    float w0 = (float)eca_w[0], w1 = (float)eca_w[1], w2 = (float)eca_w[2];
    const float* p = pooled + b * 512;
    float conv = w1 * p[c];
    if (c > 0)   conv += w0 * p[c-1];
    if (c < 511) conv += w2 * p[c+1];
    float g = 1.f / (1.f + expf(-conv));
    gate1[b * 512 + c] = 1.f + g;
}

// ------- final, layout B: RMW fp32 d_out -------
__global__ __launch_bounds__(256) void final_rmw(
    const bf16* __restrict__ y, const float* __restrict__ gate1,
    float* __restrict__ out)
{
    int b = blockIdx.z, c0 = blockIdx.y * 64, n0 = blockIdx.x * 64;
    __shared__ float ytile[64][65];
    int t = threadIdx.x;
#pragma unroll
    for (int i = 0; i < 2; i++) {
        int chunk = t * 2 + i;
        int ci = chunk >> 3, nj = (chunk & 7) * 8;
        bf16x8 v = *(const bf16x8*)&y[(size_t)b * ((size_t)N_*C_) + (size_t)(c0+ci) * 4096 + n0 + nj];
#pragma unroll
        for (int j = 0; j < 8; j++) ytile[ci][nj+j] = (float)v[j];
    }
    __syncthreads();
    int cc = t & 63, nb = t >> 6;
    float g = gate1[b * 512 + c0 + cc];
    for (int p = 0; p < 16; p++) {
        int nr = p * 4 + nb;
        size_t idx = ((size_t)b * N_ + n0 + nr) * C_ + c0 + cc;
        out[idx] = out[idx] + g * ytile[cc][nr];
    }
}

// ------- final, layout A: read bf16 x2, write fresh fp32 -------
__global__ __launch_bounds__(256) void final_fresh(
    const bf16* __restrict__ y, const bf16* __restrict__ x2b,
    const float* __restrict__ gate1, float* __restrict__ out)
{
    int b = blockIdx.z, c0 = blockIdx.y * 64, n0 = blockIdx.x * 64;
    __shared__ float ytile[64][65];
    int t = threadIdx.x;
#pragma unroll
    for (int i = 0; i < 2; i++) {
        int chunk = t * 2 + i;
        int ci = chunk >> 3, nj = (chunk & 7) * 8;
        bf16x8 v = *(const bf16x8*)&y[(size_t)b * ((size_t)N_*C_) + (size_t)(c0+ci) * 4096 + n0 + nj];
#pragma unroll
        for (int j = 0; j < 8; j++) ytile[ci][nj+j] = (float)v[j];
    }
    __syncthreads();
    int cc = t & 63, nb = t >> 6;
    float g = gate1[b * 512 + c0 + cc];
    for (int p = 0; p < 16; p++) {
        int nr = p * 4 + nb;
        size_t idx = ((size_t)b * N_ + n0 + nr) * C_ + c0 + cc;
        out[idx] = (float)x2b[idx] + g * ytile[cc][nr];
    }
}

// ====================== launcher ===========================================
extern "C" void kernel_launch(void* const* d_in, const int* in_sizes, int n_in,
                              void* d_out, int out_size, void* d_ws, size_t ws_size,
                              hipStream_t stream)
{
    float* outf = (float*)d_out;
    bf16*  outb = (bf16*)d_out;
    char* ws = (char*)d_ws;

    int*   flag    = (int*)ws;
    float* pooled  = (float*)(ws + 4096);
    float* gate1   = (float*)(ws + 20480);
    bf16* ln1_w = (bf16*)(ws + 65536);
    bf16* ln1_b = (bf16*)(ws + 67584);
    bf16* ln2_w = (bf16*)(ws + 69632);
    bf16* ln2_b = (bf16*)(ws + 71680);
    bf16* proj_b= (bf16*)(ws + 73728);
    bf16* fc2_b = (bf16*)(ws + 75776);
    bf16* eca_w = (bf16*)(ws + 77824);
    bf16* fc1_b = (bf16*)(ws + 81920);
    bf16* qkv_w = (bf16*)(ws + ((size_t)1 << 20));
    bf16* proj_w= (bf16*)(ws + (size_t)2621440);
    bf16* fc1_w = (bf16*)(ws + ((size_t)3 << 20));
    bf16* fc2_w = (bf16*)(ws + ((size_t)5 << 20));
    float* partial = (float*)(ws + ((size_t)7  << 20));
    bf16*  attnb   = (bf16*)(ws + ((size_t)15 << 20));
    bf16*  T1      = (bf16*)(ws + ((size_t)16 << 20));
    bf16*  kvbuf   = (bf16*)(ws + ((size_t)48 << 20));
    bf16*  hbuf    = kvbuf;
    bf16*  x2b     = (bf16*)(ws + ((size_t)176 << 20));

    const bool fat = ws_size >= ((size_t)212 << 20);

    // 0. sniff input dtype
    sniff_kernel<<<1, 256, 0, stream>>>((const unsigned int*)d_in[0], flag);

    // 1. convert params to bf16
    ConvArgs ca;
    const int   srcidx[12] = { 1, 2, 6, 7, 5, 11, 12, 9, 3, 4, 8, 10 };
    const unsigned offs[12] = { 65536, 67584, 69632, 71680, 73728, 75776, 77824, 81920,
                                1u<<20, 2621440u, 3u<<20, 5u<<20 };
    for (int i = 0; i < 12; i++) {
        ca.src[i] = d_in[srcidx[i]];
        ca.dstoff[i] = offs[i];
        ca.n[i] = in_sizes[srcidx[i]];
    }
    convert_params<<<dim3(512, 12), 256, 0, stream>>>(ca, ws, flag);

    // 2. LN1 -> T1
    ln_dyn_kernel<<<BN_/4, 256, 0, stream>>>(d_in[0], ln1_w, ln1_b, T1, flag);

    // 3. QKV GEMM: q (bf16) -> d_out, kv -> kvbuf  (768 tiles, 3/block)
    gemm256<bf16, EPI_QKV><<<256, 512, 0, stream>>>(
        T1, qkv_w, nullptr, nullptr, flag, outb, kvbuf, BN_, 1536, 512);

    // 4. attention
    attn_logits_mfma<<<dim3(8, 64), 256, 0, stream>>>(kvbuf, partial);
    attn_softmax_kernel<<<dim3(4, 64), 256, 0, stream>>>(partial, attnb);
    attn_apply_mfma<<<dim3(16, 64), 256, 0, stream>>>(outb, attnb, T1);

    if (fat) {
        // 5. proj + bias + residual(x) -> x2b (bf16)   (256 tiles, 1/block)
        gemm256<bf16, EPI_BIAS_RESID><<<256, 512, 0, stream>>>(
            T1, proj_w, proj_b, d_in[0], flag, x2b, nullptr, BN_, 512, 512);
        // 6. LN2: x2b -> T1
        ln_b16_kernel<<<BN_/4, 256, 0, stream>>>(x2b, ln2_w, ln2_b, T1);
        // 7. FC1 full: T1 -> hbuf (128MB)  (1024 tiles, 4/block)
        gemm256<bf16, EPI_BIAS_GELU><<<256, 512, 0, stream>>>(
            T1, fc1_w, fc1_b, nullptr, flag, hbuf, nullptr, BN_, 2048, 512);
        // 8. FC2 full: hbuf -> T1 (y)      (256 tiles, 1/block)
        gemm256<bf16, EPI_BIAS><<<256, 512, 0, stream>>>(
            hbuf, fc2_w, fc2_b, nullptr, flag, T1, nullptr, BN_, 512, 2048);
        // 9. ECA
        pooled_kernel<<<4096, 256, 0, stream>>>(T1, pooled);
        gate_kernel<<<8, 512, 0, stream>>>(pooled, eca_w, gate1);
        // 10. final: fp32 out = x2b + gate*y  (no RMW)
        final_fresh<<<dim3(64, 8, 8), 256, 0, stream>>>(T1, x2b, gate1, outf);
    } else {
        // 5. proj + bias + residual(x) -> x2 (fp32) in d_out
        gemm256<float, EPI_BIAS_RESID><<<256, 512, 0, stream>>>(
            T1, proj_w, proj_b, d_in[0], flag, outf, nullptr, BN_, 512, 512);
        // 6. LN2: d_out fp32 -> T1
        ln_f32_kernel<<<BN_/4, 256, 0, stream>>>(outf, ln2_w, ln2_b, T1);
        // 7-8. chunked FC (hbuf 64MB)
        for (int ch = 0; ch < 2; ch++) {
            bf16* Tch = T1 + (size_t)ch * 16384 * 512;
            gemm256<bf16, EPI_BIAS_GELU><<<256, 512, 0, stream>>>(
                Tch, fc1_w, fc1_b, nullptr, flag, hbuf, nullptr, 16384, 2048, 512);
            gemm256<bf16, EPI_BIAS><<<128, 512, 0, stream>>>(
                hbuf, fc2_w, fc2_b, nullptr, flag, Tch, nullptr, 16384, 512, 2048);
        }
        // 9. ECA
        pooled_kernel<<<4096, 256, 0, stream>>>(T1, pooled);
        gate_kernel<<<8, 512, 0, stream>>>(pooled, eca_w, gate1);
        // 10. final RMW on fp32 d_out
        final_rmw<<<dim3(64, 8, 8), 256, 0, stream>>>(T1, gate1, outf);
    }
}

// Round 5
// 521.939 us; speedup vs baseline: 1.0311x; 1.0311x over previous
//
#include <hip/hip_runtime.h>
#include <hip/hip_bf16.h>

typedef __bf16 bf16;
typedef __bf16 bf16x8 __attribute__((ext_vector_type(8)));
typedef float floatx4 __attribute__((ext_vector_type(4)));

#define B_    8
#define N_    4096
#define C_    512
#define BN_   32768      // B_*N_
#define HID_  2048
#define SCALE_ 0.125f    // 64^-0.5

// async 16B global -> LDS (m97 lever)
__device__ __forceinline__ void load_lds16(const void* g, void* l) {
    __builtin_amdgcn_global_load_lds(
        (const __attribute__((address_space(1))) void*)g,
        (__attribute__((address_space(3))) void*)l, 16, 0, 0);
}

// fast exact-tanh GELU: v * sigmoid(1.5957691*(v+0.044715 v^3))
__device__ __forceinline__ float gelu_fast(float v) {
    float c = fmaf(v * v, 0.044715f, 1.0f) * v;
    float e = __builtin_amdgcn_exp2f(-2.3022082f * c);
    return v * __builtin_amdgcn_rcpf(1.0f + e);
}

// ====================== dtype sniff ========================================
__global__ void sniff_kernel(const unsigned int* __restrict__ xw, int* __restrict__ flag)
{
    int t = threadIdx.x;
    int votes = 0;
#pragma unroll
    for (int i = 0; i < 4; i++) {
        unsigned w = xw[t * 4 + i];
        if (w == 0u) continue;
        unsigned a = w & 0xFFFFu;
        unsigned e = (a >> 7) & 0xFFu;
        if (a != 0u && e >= 110u && e <= 135u) votes++; else votes--;
    }
#pragma unroll
    for (int off = 32; off; off >>= 1) votes += __shfl_xor(votes, off);
    __shared__ int s[4];
    if ((t & 63) == 0) s[t >> 6] = votes;
    __syncthreads();
    if (t == 0) *flag = (s[0] + s[1] + s[2] + s[3]) > 0 ? 1 : 0;  // 1 = bf16
}

// ====================== param conversion ===================================
struct ConvArgs {
    const void* src[12];
    unsigned    dstoff[12];
    int         n[12];
};

__global__ __launch_bounds__(256) void convert_params(
    ConvArgs args, char* __restrict__ ws, const int* __restrict__ flag)
{
    int seg = blockIdx.y;
    int n = args.n[seg];
    int base = blockIdx.x * 2048;
    if (base >= n) return;
    bf16* dst = (bf16*)(ws + args.dstoff[seg]);
    const void* src = args.src[seg];
    bool isbf = (*flag != 0);
#pragma unroll
    for (int j = 0; j < 8; j++) {
        int idx = base + threadIdx.x + j * 256;
        if (idx < n) {
            float v = isbf ? (float)((const bf16*)src)[idx]
                           : ((const float*)src)[idx];
            dst[idx] = (bf16)v;
        }
    }
}

// ====================== LayerNorm variants =================================
__device__ __forceinline__ void ln_core(float f[8], const bf16* w, const bf16* b,
                                        int lane, bf16* outp)
{
    float s = 0.f, sq = 0.f;
#pragma unroll
    for (int j = 0; j < 8; j++) { s += f[j]; sq += f[j]*f[j]; }
#pragma unroll
    for (int off = 32; off; off >>= 1) { s += __shfl_xor(s, off); sq += __shfl_xor(sq, off); }
    float mean = s * (1.f/512.f);
    float var  = sq * (1.f/512.f) - mean*mean;
    float inv  = rsqrtf(var + 1e-5f);
    bf16x8 wv = *(const bf16x8*)(w + lane*8);
    bf16x8 bv = *(const bf16x8*)(b + lane*8);
    bf16x8 o;
#pragma unroll
    for (int j = 0; j < 8; j++) o[j] = (bf16)((f[j]-mean)*inv*(float)wv[j] + (float)bv[j]);
    *(bf16x8*)outp = o;
}

__global__ __launch_bounds__(256) void ln_dyn_kernel(
    const void* __restrict__ xv, const bf16* __restrict__ w,
    const bf16* __restrict__ b, bf16* __restrict__ out, const int* __restrict__ flag)
{
    int wave = threadIdx.x >> 6, lane = threadIdx.x & 63;
    size_t row = (size_t)blockIdx.x * 4 + wave;
    float f[8];
    if (*flag) {
        bf16x8 v = *(const bf16x8*)((const bf16*)xv + row * C_ + lane * 8);
#pragma unroll
        for (int j = 0; j < 8; j++) f[j] = (float)v[j];
    } else {
        const float4* p = (const float4*)((const float*)xv + row * C_ + lane * 8);
        float4 v0 = p[0], v1 = p[1];
        f[0]=v0.x; f[1]=v0.y; f[2]=v0.z; f[3]=v0.w;
        f[4]=v1.x; f[5]=v1.y; f[6]=v1.z; f[7]=v1.w;
    }
    ln_core(f, w, b, lane, out + row * C_ + lane*8);
}

__global__ __launch_bounds__(256) void ln_b16_kernel(
    const bf16* __restrict__ x, const bf16* __restrict__ w,
    const bf16* __restrict__ b, bf16* __restrict__ out)
{
    int wave = threadIdx.x >> 6, lane = threadIdx.x & 63;
    size_t row = (size_t)blockIdx.x * 4 + wave;
    bf16x8 v = *(const bf16x8*)(x + row * C_ + lane * 8);
    float f[8];
#pragma unroll
    for (int j = 0; j < 8; j++) f[j] = (float)v[j];
    ln_core(f, w, b, lane, out + row * C_ + lane*8);
}

__global__ __launch_bounds__(256) void ln_f32_kernel(
    const float* __restrict__ x, const bf16* __restrict__ w,
    const bf16* __restrict__ b, bf16* __restrict__ out)
{
    int wave = threadIdx.x >> 6, lane = threadIdx.x & 63;
    size_t row = (size_t)blockIdx.x * 4 + wave;
    const float4* p = (const float4*)(x + row * C_ + lane * 8);
    float4 v0 = p[0], v1 = p[1];
    float f[8] = { v0.x, v0.y, v0.z, v0.w, v1.x, v1.y, v1.z, v1.w };
    ln_core(f, w, b, lane, out + row * C_ + lane*8);
}

// ====================== 256x256 MFMA GEMM (persistent, addr-hoisted) =======
// R4 post-mortem: all structures stuck 22-27% while m198 (same shape,
// unswizzled) hits 45.7% -> the stall is per-phase address VALU: swizzled
// LDS read addrs + runtime slot base recomputed each phase (VALUBusy 33-39%
// with only ~22% MFMA; VGPR 108-124 shows compiler remat'd instead of
// hoisting). Fix: (1) hoist the 12 swizzled read pointers pa[4][2]/pb[2][2]
// into regs before the tile loop; (2) unroll K-loop by 2 so slot parity S is
// a literal -> slot/half select becomes ds_read offset: immediate
// (S*32768 + H*16384 bytes <= 49152, fits 16-bit); (3) m201 phase shape
// {reads; stage; [vmcnt]; barrier; lgkm0; setprio MFMA}, ONE barrier/phase
// (release map tolerates <1-phase skew: every stage targets a slot last
// read >= 2 phases prior), gray-code frag reuse (24 ds_read_b128/K-tile).
// Prologue restored to R3 order (R4's order left B1(0) uncovered by the
// vmcnt(4) cut - latent race). vmcnt(4)@q3 proof unchanged.
enum { EPI_NONE = 0, EPI_BIAS = 1, EPI_BIAS_RESID = 2, EPI_BIAS_GELU = 3, EPI_QKV = 4 };

#define MM(AF, BF, AH, BH)                                                     \
    __builtin_amdgcn_s_setprio(1);                                             \
    _Pragma("unroll") for (int mi = 0; mi < 4; mi++)                           \
    _Pragma("unroll") for (int ni = 0; ni < 2; ni++)                           \
    _Pragma("unroll") for (int ks = 0; ks < 2; ks++)                           \
        acc[(AH)*4+mi][(BH)*2+ni] = __builtin_amdgcn_mfma_f32_16x16x32_bf16(   \
            AF[mi][ks], BF[ni][ks], acc[(AH)*4+mi][(BH)*2+ni], 0, 0, 0);       \
    __builtin_amdgcn_s_setprio(0);
#define STAGE2(GB, LB)                                                         \
    { load_lds16((GB) + goff0, (LB) + loff0);                                  \
      load_lds16((GB) + goff1, (LB) + loff1); }

// One K-tile: 4 phases, slot parity S is a compile-time literal.
#define KTILE(KT, S)                                                           \
{                                                                              \
    bf16x8 af[4][2], bf0[2][2], bf1[2][2];                                     \
    /* q0: reads A0,B0 (12); stage A1(next); MFMA (0,0) */                     \
    _Pragma("unroll") for (int mi = 0; mi < 4; mi++)                           \
    _Pragma("unroll") for (int ks = 0; ks < 2; ks++)                           \
        af[mi][ks] = *(const bf16x8*)(pa[mi][ks] + (S) * 16384);               \
    _Pragma("unroll") for (int ni = 0; ni < 2; ni++)                           \
    _Pragma("unroll") for (int ks = 0; ks < 2; ks++)                           \
        bf0[ni][ks] = *(const bf16x8*)(pb[ni][ks] + (S) * 16384);              \
    { const bf16* sp = ((KT) + 1 < NKT)                                        \
          ? A + (size_t)(m0 + 128) * K + (size_t)((KT) + 1) * 64               \
          : (hn ? A + (size_t)(m0n + 128) * K : nullptr);                      \
      if (sp) STAGE2(sp, &Asl[(S) ^ 1][1][0][0]); }                            \
    __builtin_amdgcn_s_barrier();                                              \
    asm volatile("s_waitcnt lgkmcnt(0)");                                      \
    __builtin_amdgcn_sched_barrier(0);                                         \
    MM(af, bf0, 0, 0)                                                          \
    /* q1: reads B1 (4); stage B1(next); MFMA (0,1) */                         \
    _Pragma("unroll") for (int ni = 0; ni < 2; ni++)                           \
    _Pragma("unroll") for (int ks = 0; ks < 2; ks++)                           \
        bf1[ni][ks] = *(const bf16x8*)(pb[ni][ks] + (S) * 16384 + 8192);       \
    { const bf16* sp = ((KT) + 1 < NKT)                                        \
          ? W + (size_t)(n0 + 128) * K + (size_t)((KT) + 1) * 64               \
          : (hn ? W + (size_t)(n0n + 128) * K : nullptr);                      \
      if (sp) STAGE2(sp, &Bsl[(S) ^ 1][1][0][0]); }                            \
    __builtin_amdgcn_s_barrier();                                              \
    asm volatile("s_waitcnt lgkmcnt(0)");                                      \
    __builtin_amdgcn_sched_barrier(0);                                         \
    MM(af, bf1, 0, 1)                                                          \
    /* q2: reads A1 (8); stage A0(next2); MFMA (1,1) */                        \
    _Pragma("unroll") for (int mi = 0; mi < 4; mi++)                           \
    _Pragma("unroll") for (int ks = 0; ks < 2; ks++)                           \
        af[mi][ks] = *(const bf16x8*)(pa[mi][ks] + (S) * 16384 + 8192);        \
    { const bf16* sp = ((KT) + 2 < NKT)                                        \
          ? A + (size_t)m0 * K + (size_t)((KT) + 2) * 64                       \
          : (hn ? A + (size_t)m0n * K + (size_t)((KT) + 2 - NKT) * 64          \
               : nullptr);                                                     \
      if (sp) STAGE2(sp, &Asl[(S)][0][0][0]); }                                \
    __builtin_amdgcn_s_barrier();                                              \
    asm volatile("s_waitcnt lgkmcnt(0)");                                      \
    __builtin_amdgcn_sched_barrier(0);                                         \
    MM(af, bf1, 1, 1)                                                          \
    /* q3: no reads; stage B0(next2); vmcnt; MFMA (1,0) reuse bf0 */           \
    { const bf16* sp = ((KT) + 2 < NKT)                                        \
          ? W + (size_t)n0 * K + (size_t)((KT) + 2) * 64                       \
          : (hn ? W + (size_t)n0n * K + (size_t)((KT) + 2 - NKT) * 64          \
               : nullptr);                                                     \
      if (sp) STAGE2(sp, &Bsl[(S)][0][0][0]); }                                \
    if ((KT) + 1 < NKT || hn) {                                                \
        if ((KT) + 2 < NKT || hn) asm volatile("s_waitcnt vmcnt(4)");          \
        else                      asm volatile("s_waitcnt vmcnt(0)");          \
    }                                                                          \
    __builtin_amdgcn_s_barrier();                                              \
    MM(af, bf0, 1, 0)                                                          \
}

template<typename OutT, int EPI>
__global__ __launch_bounds__(512, 2) void gemm256(
    const bf16* __restrict__ A, const bf16* __restrict__ W,
    const bf16* __restrict__ bias, const void* __restrict__ resid,
    const int* __restrict__ flag,
    OutT* __restrict__ Cout, bf16* __restrict__ Cout2, int M, int Nn, int K)
{
    __shared__ bf16 Asl[2][2][128][64];   // [slot][half][row][k]  64 KiB
    __shared__ bf16 Bsl[2][2][128][64];   // 64 KiB
    const int t = threadIdx.x;
    const int wv = t >> 6, lane = t & 63;
    const int quad = lane >> 4, l16 = lane & 15;
    const int wm = wv >> 2, wn = wv & 3;          // wave tile: 128 rows x 64 cols
    const int Nt = Nn >> 8;
    const int total = (M >> 8) * Nt;
    const int G = gridDim.x;
    const int NKT = K >> 6;                        // BK=64 K-tiles (even)

    // hoisted swizzled LDS read pointers (12 regs); slot/half via offset imm
    const bf16* pa[4][2];
    const bf16* pb[2][2];
#pragma unroll
    for (int mi = 0; mi < 4; mi++) {
        int row = wm * 64 + mi * 16 + l16;
#pragma unroll
        for (int ks = 0; ks < 2; ks++)
            pa[mi][ks] = &Asl[0][0][0][0] + row * 64 +
                         ((ks * 32 + quad * 8) ^ ((row & 7) << 3));
    }
#pragma unroll
    for (int ni = 0; ni < 2; ni++) {
        int row = wn * 32 + ni * 16 + l16;
#pragma unroll
        for (int ks = 0; ks < 2; ks++)
            pb[ni][ks] = &Bsl[0][0][0][0] + row * 64 +
                         ((ks * 32 + quad * 8) ^ ((row & 7) << 3));
    }

    // loop-invariant stage addressing (16B chunk c: row=c>>3, swizzled slot)
    const int c0 = t, c1 = 512 + t;
    const int r0 = c0 >> 3, r1 = c1 >> 3;
    const size_t goff0 = (size_t)r0 * K + (size_t)(((c0 & 7) ^ (r0 & 7)) * 8);
    const size_t goff1 = (size_t)r1 * K + (size_t)(((c1 & 7) ^ (r1 & 7)) * 8);
    const int loff0 = c0 * 8, loff1 = c1 * 8;

    int id = blockIdx.x;
    if (id >= total) return;
    int m0 = (((id >> 3) / Nt) * 8 + (id & 7)) * 256;
    int n0 = ((id >> 3) % Nt) * 256;

    // ---- prologue (R3 order): K-tile 0 fully + first halves of K-tile 1 ----
    STAGE2(A + (size_t)m0 * K,         &Asl[0][0][0][0]);  // A0(0)
    STAGE2(W + (size_t)n0 * K,         &Bsl[0][0][0][0]);  // B0(0)
    STAGE2(A + (size_t)(m0 + 128) * K, &Asl[0][1][0][0]);  // A1(0)
    STAGE2(W + (size_t)(n0 + 128) * K, &Bsl[0][1][0][0]);  // B1(0)
    STAGE2(A + (size_t)m0 * K + 64,    &Asl[1][0][0][0]);  // A0(1)
    STAGE2(W + (size_t)n0 * K + 64,    &Bsl[1][0][0][0]);  // B0(1)
    asm volatile("s_waitcnt vmcnt(4)");   // K-tile 0 resident; A0(1),B0(1) in flight
    __builtin_amdgcn_s_barrier();

    for (;;) {
        const int idn = id + G;
        const bool hn = idn < total;
        int m0n = 0, n0n = 0;
        if (hn) {
            m0n = (((idn >> 3) / Nt) * 8 + (idn & 7)) * 256;
            n0n = ((idn >> 3) % Nt) * 256;
        }

        floatx4 acc[8][4] = {};

        for (int kt = 0; kt < NKT; kt += 2) {
            KTILE(kt, 0)
            KTILE(kt + 1, 1)
        }

        // ---- epilogue (next tile's K-tile 0 already resident) ----
        size_t ldc = (size_t)Nn; int csub = 0; bool to2 = false;
        if (EPI == EPI_QKV) {
            if (n0 >= 512) { to2 = true; ldc = 1024; csub = 512; }
            else           { ldc = 512; }
        }
        bool isbf = false;
        if (EPI == EPI_BIAS_RESID) isbf = (*flag != 0);

#pragma unroll
        for (int mg = 0; mg < 8; mg++) {
            int rowg = m0 + (mg >> 2) * 128 + wm * 64 + (mg & 3) * 16 + quad * 4;
#pragma unroll
            for (int ng = 0; ng < 4; ng++) {
                int col = n0 + (ng >> 1) * 128 + wn * 32 + (ng & 1) * 16 + l16;
                float bv = (EPI == EPI_BIAS || EPI == EPI_BIAS_RESID || EPI == EPI_BIAS_GELU)
                           ? (float)bias[col] : 0.f;
#pragma unroll
                for (int r = 0; r < 4; r++) {
                    size_t idx = (size_t)(rowg + r) * ldc + (col - csub);
                    float v = acc[mg][ng][r] + bv;
                    if (EPI == EPI_BIAS_RESID) {
                        float rres = isbf ? (float)((const bf16*)resid)[idx]
                                          : ((const float*)resid)[idx];
                        v += rres;
                    }
                    if (EPI == EPI_BIAS_GELU)  v = gelu_fast(v);
                    if (EPI == EPI_QKV && to2) Cout2[idx] = (bf16)v;
                    else                       Cout[idx]  = (OutT)v;
                }
            }
        }

        if (!hn) break;
        id = idn; m0 = m0n; n0 = n0n;
    }
}

// ====================== attention (MFMA) ===================================
// grid (8 slices, 64 bh): partial[(bh*8+s)*4096 + d*64+e] over 512 tokens
__global__ __launch_bounds__(256) void attn_logits_mfma(
    const bf16* __restrict__ kv, float* __restrict__ partial)
{
    __shared__ bf16 Kt[64][136];
    __shared__ bf16 Vt[64][136];
    int s = blockIdx.x, bh = blockIdx.y, b = bh >> 3, h = bh & 7;
    int t = threadIdx.x, wave = t >> 6, lane = t & 63;
    int quad = lane >> 4, l16 = lane & 15;
    floatx4 acc[4] = {};
    for (int c = 0; c < 4; c++) {
        int n0 = s * 512 + c * 128;
        {
            int isv = t >> 7;
            int r   = t & 127;
            const bf16* gp = &kv[((size_t)b * N_ + n0 + r) * 1024 + h * 64 + isv * 512];
            bf16x8 rowv[8];
#pragma unroll
            for (int u = 0; u < 8; u++) rowv[u] = *(const bf16x8*)(gp + u * 8);
            bf16 (*dst)[136] = isv ? Vt : Kt;
#pragma unroll
            for (int u = 0; u < 8; u++)
#pragma unroll
                for (int jj = 0; jj < 8; jj++)
                    dst[u * 8 + jj][r] = rowv[u][jj];
        }
        __syncthreads();
#pragma unroll
        for (int ks = 0; ks < 4; ks++) {
            bf16x8 af = *(const bf16x8*)&Kt[wave * 16 + l16][ks * 32 + quad * 8];
#pragma unroll
            for (int ni = 0; ni < 4; ni++) {
                bf16x8 bfv = *(const bf16x8*)&Vt[ni * 16 + l16][ks * 32 + quad * 8];
                acc[ni] = __builtin_amdgcn_mfma_f32_16x16x32_bf16(af, bfv, acc[ni], 0, 0, 0);
            }
        }
        __syncthreads();
    }
    float* p = partial + ((size_t)bh * 8 + s) * 4096;
#pragma unroll
    for (int ni = 0; ni < 4; ni++)
#pragma unroll
        for (int r = 0; r < 4; r++)
            p[(wave * 16 + quad * 4 + r) * 64 + ni * 16 + l16] = acc[ni][r];
}

// softmax: grid (4, 64); block handles 16 d rows (wave*4 + r)
__global__ __launch_bounds__(256) void attn_softmax_kernel(
    const float* __restrict__ partial, bf16* __restrict__ attnb)
{
    int bh = blockIdx.y;
    int wave = threadIdx.x >> 6, lane = threadIdx.x & 63;
    for (int r = 0; r < 4; r++) {
        int d = blockIdx.x * 16 + wave * 4 + r;
        float v = 0.f;
#pragma unroll
        for (int s = 0; s < 8; s++) v += partial[((size_t)bh*8 + s)*4096 + d*64 + lane];
        v *= SCALE_;
        float m = v;
#pragma unroll
        for (int off = 32; off; off >>= 1) m = fmaxf(m, __shfl_xor(m, off));
        float p = expf(v - m);
        float sum = p;
#pragma unroll
        for (int off = 32; off; off >>= 1) sum += __shfl_xor(sum, off);
        attnb[(size_t)bh*4096 + d*64 + lane] = (bf16)(p / sum);
    }
}

// apply: outT[n][h*64+d] = sum_e attn[d][e] * q[n][h*64+e]
__global__ __launch_bounds__(256) void attn_apply_mfma(
    const bf16* __restrict__ q, const bf16* __restrict__ attnb,
    bf16* __restrict__ outT)
{
    int bh = blockIdx.y, b = bh >> 3, h = bh & 7;
    int t = threadIdx.x, wave = t >> 6, lane = t & 63;
    int quad = lane >> 4, l16 = lane & 15;
    int nbase = blockIdx.x * 256 + wave * 64;
    bf16x8 bfrag[4][2];
#pragma unroll
    for (int di = 0; di < 4; di++)
#pragma unroll
        for (int ks = 0; ks < 2; ks++)
            bfrag[di][ks] = *(const bf16x8*)&attnb[(size_t)bh*4096 + (di*16 + l16)*64 + ks*32 + quad*8];
    floatx4 acc[4][4] = {};
#pragma unroll
    for (int mi = 0; mi < 4; mi++) {
#pragma unroll
        for (int ks = 0; ks < 2; ks++) {
            bf16x8 af = *(const bf16x8*)&q[((size_t)b*N_ + nbase + mi*16 + l16)*512 + h*64 + ks*32 + quad*8];
#pragma unroll
            for (int di = 0; di < 4; di++)
                acc[mi][di] = __builtin_amdgcn_mfma_f32_16x16x32_bf16(af, bfrag[di][ks], acc[mi][di], 0, 0, 0);
        }
    }
#pragma unroll
    for (int mi = 0; mi < 4; mi++)
#pragma unroll
        for (int di = 0; di < 4; di++)
#pragma unroll
            for (int r = 0; r < 4; r++)
                outT[((size_t)b*N_ + nbase + mi*16 + quad*4 + r)*512 + h*64 + di*16 + l16] =
                    (bf16)acc[mi][di][r];
}

// ====================== ECA ================================================
__global__ __launch_bounds__(256) void pooled_kernel(
    const bf16* __restrict__ y, float* __restrict__ pooled)
{
    int bc = blockIdx.x;
    const bf16* p = y + (size_t)bc * 4096 + threadIdx.x * 16;
    float s = 0.f;
#pragma unroll
    for (int i = 0; i < 2; i++) {
        bf16x8 v = *(const bf16x8*)(p + i*8);
#pragma unroll
        for (int j = 0; j < 8; j++) s += (float)v[j];
    }
#pragma unroll
    for (int off = 32; off; off >>= 1) s += __shfl_xor(s, off);
    __shared__ float red[4];
    if ((threadIdx.x & 63) == 0) red[threadIdx.x >> 6] = s;
    __syncthreads();
    if (threadIdx.x == 0)
        pooled[bc] = (red[0] + red[1] + red[2] + red[3]) * (1.f/4096.f);
}

__global__ void gate_kernel(const float* __restrict__ pooled,
                            const bf16* __restrict__ eca_w, float* __restrict__ gate1)
{
    int c = threadIdx.x, b = blockIdx.x;
    float w0 = (float)eca_w[0], w1 = (float)eca_w[1], w2 = (float)eca_w[2];
    const float* p = pooled + b * 512;
    float conv = w1 * p[c];
    if (c > 0)   conv += w0 * p[c-1];
    if (c < 511) conv += w2 * p[c+1];
    float g = 1.f / (1.f + expf(-conv));
    gate1[b * 512 + c] = 1.f + g;
}

// ------- final, layout B: RMW fp32 d_out -------
__global__ __launch_bounds__(256) void final_rmw(
    const bf16* __restrict__ y, const float* __restrict__ gate1,
    float* __restrict__ out)
{
    int b = blockIdx.z, c0 = blockIdx.y * 64, n0 = blockIdx.x * 64;
    __shared__ float ytile[64][65];
    int t = threadIdx.x;
#pragma unroll
    for (int i = 0; i < 2; i++) {
        int chunk = t * 2 + i;
        int ci = chunk >> 3, nj = (chunk & 7) * 8;
        bf16x8 v = *(const bf16x8*)&y[(size_t)b * ((size_t)N_*C_) + (size_t)(c0+ci) * 4096 + n0 + nj];
#pragma unroll
        for (int j = 0; j < 8; j++) ytile[ci][nj+j] = (float)v[j];
    }
    __syncthreads();
    int cc = t & 63, nb = t >> 6;
    float g = gate1[b * 512 + c0 + cc];
    for (int p = 0; p < 16; p++) {
        int nr = p * 4 + nb;
        size_t idx = ((size_t)b * N_ + n0 + nr) * C_ + c0 + cc;
        out[idx] = out[idx] + g * ytile[cc][nr];
    }
}

// ------- final, layout A: read bf16 x2, write fresh fp32 -------
__global__ __launch_bounds__(256) void final_fresh(
    const bf16* __restrict__ y, const bf16* __restrict__ x2b,
    const float* __restrict__ gate1, float* __restrict__ out)
{
    int b = blockIdx.z, c0 = blockIdx.y * 64, n0 = blockIdx.x * 64;
    __shared__ float ytile[64][65];
    int t = threadIdx.x;
#pragma unroll
    for (int i = 0; i < 2; i++) {
        int chunk = t * 2 + i;
        int ci = chunk >> 3, nj = (chunk & 7) * 8;
        bf16x8 v = *(const bf16x8*)&y[(size_t)b * ((size_t)N_*C_) + (size_t)(c0+ci) * 4096 + n0 + nj];
#pragma unroll
        for (int j = 0; j < 8; j++) ytile[ci][nj+j] = (float)v[j];
    }
    __syncthreads();
    int cc = t & 63, nb = t >> 6;
    float g = gate1[b * 512 + c0 + cc];
    for (int p = 0; p < 16; p++) {
        int nr = p * 4 + nb;
        size_t idx = ((size_t)b * N_ + n0 + nr) * C_ + c0 + cc;
        out[idx] = (float)x2b[idx] + g * ytile[cc][nr];
    }
}

// ====================== launcher ===========================================
extern "C" void kernel_launch(void* const* d_in, const int* in_sizes, int n_in,
                              void* d_out, int out_size, void* d_ws, size_t ws_size,
                              hipStream_t stream)
{
    float* outf = (float*)d_out;
    bf16*  outb = (bf16*)d_out;
    char* ws = (char*)d_ws;

    int*   flag    = (int*)ws;
    float* pooled  = (float*)(ws + 4096);
    float* gate1   = (float*)(ws + 20480);
    bf16* ln1_w = (bf16*)(ws + 65536);
    bf16* ln1_b = (bf16*)(ws + 67584);
    bf16* ln2_w = (bf16*)(ws + 69632);
    bf16* ln2_b = (bf16*)(ws + 71680);
    bf16* proj_b= (bf16*)(ws + 73728);
    bf16* fc2_b = (bf16*)(ws + 75776);
    bf16* eca_w = (bf16*)(ws + 77824);
    bf16* fc1_b = (bf16*)(ws + 81920);
    bf16* qkv_w = (bf16*)(ws + ((size_t)1 << 20));
    bf16* proj_w= (bf16*)(ws + (size_t)2621440);
    bf16* fc1_w = (bf16*)(ws + ((size_t)3 << 20));
    bf16* fc2_w = (bf16*)(ws + ((size_t)5 << 20));
    float* partial = (float*)(ws + ((size_t)7  << 20));
    bf16*  attnb   = (bf16*)(ws + ((size_t)15 << 20));
    bf16*  T1      = (bf16*)(ws + ((size_t)16 << 20));
    bf16*  kvbuf   = (bf16*)(ws + ((size_t)48 << 20));
    bf16*  hbuf    = kvbuf;
    bf16*  x2b     = (bf16*)(ws + ((size_t)176 << 20));

    const bool fat = ws_size >= ((size_t)212 << 20);

    // 0. sniff input dtype
    sniff_kernel<<<1, 256, 0, stream>>>((const unsigned int*)d_in[0], flag);

    // 1. convert params to bf16
    ConvArgs ca;
    const int   srcidx[12] = { 1, 2, 6, 7, 5, 11, 12, 9, 3, 4, 8, 10 };
    const unsigned offs[12] = { 65536, 67584, 69632, 71680, 73728, 75776, 77824, 81920,
                                1u<<20, 2621440u, 3u<<20, 5u<<20 };
    for (int i = 0; i < 12; i++) {
        ca.src[i] = d_in[srcidx[i]];
        ca.dstoff[i] = offs[i];
        ca.n[i] = in_sizes[srcidx[i]];
    }
    convert_params<<<dim3(512, 12), 256, 0, stream>>>(ca, ws, flag);

    // 2. LN1 -> T1
    ln_dyn_kernel<<<BN_/4, 256, 0, stream>>>(d_in[0], ln1_w, ln1_b, T1, flag);

    // 3. QKV GEMM: q (bf16) -> d_out, kv -> kvbuf  (768 tiles, 3/block)
    gemm256<bf16, EPI_QKV><<<256, 512, 0, stream>>>(
        T1, qkv_w, nullptr, nullptr, flag, outb, kvbuf, BN_, 1536, 512);

    // 4. attention
    attn_logits_mfma<<<dim3(8, 64), 256, 0, stream>>>(kvbuf, partial);
    attn_softmax_kernel<<<dim3(4, 64), 256, 0, stream>>>(partial, attnb);
    attn_apply_mfma<<<dim3(16, 64), 256, 0, stream>>>(outb, attnb, T1);

    if (fat) {
        // 5. proj + bias + residual(x) -> x2b (bf16)   (256 tiles, 1/block)
        gemm256<bf16, EPI_BIAS_RESID><<<256, 512, 0, stream>>>(
            T1, proj_w, proj_b, d_in[0], flag, x2b, nullptr, BN_, 512, 512);
        // 6. LN2: x2b -> T1
        ln_b16_kernel<<<BN_/4, 256, 0, stream>>>(x2b, ln2_w, ln2_b, T1);
        // 7. FC1 full: T1 -> hbuf (128MB)  (1024 tiles, 4/block)
        gemm256<bf16, EPI_BIAS_GELU><<<256, 512, 0, stream>>>(
            T1, fc1_w, fc1_b, nullptr, flag, hbuf, nullptr, BN_, 2048, 512);
        // 8. FC2 full: hbuf -> T1 (y)      (256 tiles, 1/block)
        gemm256<bf16, EPI_BIAS><<<256, 512, 0, stream>>>(
            hbuf, fc2_w, fc2_b, nullptr, flag, T1, nullptr, BN_, 512, 2048);
        // 9. ECA
        pooled_kernel<<<4096, 256, 0, stream>>>(T1, pooled);
        gate_kernel<<<8, 512, 0, stream>>>(pooled, eca_w, gate1);
        // 10. final: fp32 out = x2b + gate*y  (no RMW)
        final_fresh<<<dim3(64, 8, 8), 256, 0, stream>>>(T1, x2b, gate1, outf);
    } else {
        // 5. proj + bias + residual(x) -> x2 (fp32) in d_out
        gemm256<float, EPI_BIAS_RESID><<<256, 512, 0, stream>>>(
            T1, proj_w, proj_b, d_in[0], flag, outf, nullptr, BN_, 512, 512);
        // 6. LN2: d_out fp32 -> T1
        ln_f32_kernel<<<BN_/4, 256, 0, stream>>>(outf, ln2_w, ln2_b, T1);
        // 7-8. chunked FC (hbuf 64MB)
        for (int ch = 0; ch < 2; ch++) {
            bf16* Tch = T1 + (size_t)ch * 16384 * 512;
            gemm256<bf16, EPI_BIAS_GELU><<<256, 512, 0, stream>>>(
                Tch, fc1_w, fc1_b, nullptr, flag, hbuf, nullptr, 16384, 2048, 512);
            gemm256<bf16, EPI_BIAS><<<128, 512, 0, stream>>>(
                hbuf, fc2_w, fc2_b, nullptr, flag, Tch, nullptr, 16384, 512, 2048);
        }
        // 9. ECA
        pooled_kernel<<<4096, 256, 0, stream>>>(T1, pooled);
        gate_kernel<<<8, 512, 0, stream>>>(pooled, eca_w, gate1);
        // 10. final RMW on fp32 d_out
        final_rmw<<<dim3(64, 8, 8), 256, 0, stream>>>(T1, gate1, outf);
    }
}

// Round 6
// 513.086 us; speedup vs baseline: 1.0488x; 1.0173x over previous
//
#include <hip/hip_runtime.h>
#include <hip/hip_bf16.h>

typedef __bf16 bf16;
typedef __bf16 bf16x8 __attribute__((ext_vector_type(8)));
typedef float floatx4 __attribute__((ext_vector_type(4)));

#define B_    8
#define N_    4096
#define C_    512
#define BN_   32768      // B_*N_
#define HID_  2048
#define SCALE_ 0.125f    // 64^-0.5

// async 16B global -> LDS (m97 lever)
__device__ __forceinline__ void load_lds16(const void* g, void* l) {
    __builtin_amdgcn_global_load_lds(
        (const __attribute__((address_space(1))) void*)g,
        (__attribute__((address_space(3))) void*)l, 16, 0, 0);
}

// fast exact-tanh GELU: v * sigmoid(1.5957691*(v+0.044715 v^3))
__device__ __forceinline__ float gelu_fast(float v) {
    float c = fmaf(v * v, 0.044715f, 1.0f) * v;
    float e = __builtin_amdgcn_exp2f(-2.3022082f * c);
    return v * __builtin_amdgcn_rcpf(1.0f + e);
}

// ====================== dtype sniff ========================================
__global__ void sniff_kernel(const unsigned int* __restrict__ xw, int* __restrict__ flag)
{
    int t = threadIdx.x;
    int votes = 0;
#pragma unroll
    for (int i = 0; i < 4; i++) {
        unsigned w = xw[t * 4 + i];
        if (w == 0u) continue;
        unsigned a = w & 0xFFFFu;
        unsigned e = (a >> 7) & 0xFFu;
        if (a != 0u && e >= 110u && e <= 135u) votes++; else votes--;
    }
#pragma unroll
    for (int off = 32; off; off >>= 1) votes += __shfl_xor(votes, off);
    __shared__ int s[4];
    if ((t & 63) == 0) s[t >> 6] = votes;
    __syncthreads();
    if (t == 0) *flag = (s[0] + s[1] + s[2] + s[3]) > 0 ? 1 : 0;  // 1 = bf16
}

// ====================== param conversion ===================================
struct ConvArgs {
    const void* src[12];
    unsigned    dstoff[12];
    int         n[12];
};

__global__ __launch_bounds__(256) void convert_params(
    ConvArgs args, char* __restrict__ ws, const int* __restrict__ flag)
{
    int seg = blockIdx.y;
    int n = args.n[seg];
    int base = blockIdx.x * 2048;
    if (base >= n) return;
    bf16* dst = (bf16*)(ws + args.dstoff[seg]);
    const void* src = args.src[seg];
    bool isbf = (*flag != 0);
#pragma unroll
    for (int j = 0; j < 8; j++) {
        int idx = base + threadIdx.x + j * 256;
        if (idx < n) {
            float v = isbf ? (float)((const bf16*)src)[idx]
                           : ((const float*)src)[idx];
            dst[idx] = (bf16)v;
        }
    }
}

// ====================== LayerNorm variants =================================
__device__ __forceinline__ void ln_core(float f[8], const bf16* w, const bf16* b,
                                        int lane, bf16* outp)
{
    float s = 0.f, sq = 0.f;
#pragma unroll
    for (int j = 0; j < 8; j++) { s += f[j]; sq += f[j]*f[j]; }
#pragma unroll
    for (int off = 32; off; off >>= 1) { s += __shfl_xor(s, off); sq += __shfl_xor(sq, off); }
    float mean = s * (1.f/512.f);
    float var  = sq * (1.f/512.f) - mean*mean;
    float inv  = rsqrtf(var + 1e-5f);
    bf16x8 wv = *(const bf16x8*)(w + lane*8);
    bf16x8 bv = *(const bf16x8*)(b + lane*8);
    bf16x8 o;
#pragma unroll
    for (int j = 0; j < 8; j++) o[j] = (bf16)((f[j]-mean)*inv*(float)wv[j] + (float)bv[j]);
    *(bf16x8*)outp = o;
}

__global__ __launch_bounds__(256) void ln_dyn_kernel(
    const void* __restrict__ xv, const bf16* __restrict__ w,
    const bf16* __restrict__ b, bf16* __restrict__ out, const int* __restrict__ flag)
{
    int wave = threadIdx.x >> 6, lane = threadIdx.x & 63;
    size_t row = (size_t)blockIdx.x * 4 + wave;
    float f[8];
    if (*flag) {
        bf16x8 v = *(const bf16x8*)((const bf16*)xv + row * C_ + lane * 8);
#pragma unroll
        for (int j = 0; j < 8; j++) f[j] = (float)v[j];
    } else {
        const float4* p = (const float4*)((const float*)xv + row * C_ + lane * 8);
        float4 v0 = p[0], v1 = p[1];
        f[0]=v0.x; f[1]=v0.y; f[2]=v0.z; f[3]=v0.w;
        f[4]=v1.x; f[5]=v1.y; f[6]=v1.z; f[7]=v1.w;
    }
    ln_core(f, w, b, lane, out + row * C_ + lane*8);
}

__global__ __launch_bounds__(256) void ln_b16_kernel(
    const bf16* __restrict__ x, const bf16* __restrict__ w,
    const bf16* __restrict__ b, bf16* __restrict__ out)
{
    int wave = threadIdx.x >> 6, lane = threadIdx.x & 63;
    size_t row = (size_t)blockIdx.x * 4 + wave;
    bf16x8 v = *(const bf16x8*)(x + row * C_ + lane * 8);
    float f[8];
#pragma unroll
    for (int j = 0; j < 8; j++) f[j] = (float)v[j];
    ln_core(f, w, b, lane, out + row * C_ + lane*8);
}

__global__ __launch_bounds__(256) void ln_f32_kernel(
    const float* __restrict__ x, const bf16* __restrict__ w,
    const bf16* __restrict__ b, bf16* __restrict__ out)
{
    int wave = threadIdx.x >> 6, lane = threadIdx.x & 63;
    size_t row = (size_t)blockIdx.x * 4 + wave;
    const float4* p = (const float4*)(x + row * C_ + lane * 8);
    float4 v0 = p[0], v1 = p[1];
    float f[8] = { v0.x, v0.y, v0.z, v0.w, v1.x, v1.y, v1.z, v1.w };
    ln_core(f, w, b, lane, out + row * C_ + lane*8);
}

// ====================== 256x256 MFMA GEMM (persistent, read-ahead) =========
// R5 post-mortem: addr VALU fixed (non-MFMA VALU ~6%) but phase still =
// reads + lgkmcnt(0) + MFMA serialized -> 30% MfmaUtil. R6:
//  (1) ONE-PHASE-AHEAD reads with zero same-phase consumption:
//      q0 -> bf1 (used q1,q2); q1 -> afO (used q2,q3); q2 -> none;
//      q3 -> afE' (next tile/K-tile, after vmcnt+barrier) and bf0' AFTER
//      the q3 MFMA (no reg double-buffer; partial hiding under q0's
//      stage+barrier). No explicit lgkmcnt(0): plain C++ LDS reads, the
//      compiler inserts exact partial waits (each group has ~1 phase).
//      RAW: q3's afE'/bf0' slots staged at q2/q3(t-1) = 5th+-oldest at
//      the q3(t) vmcnt(4) -> retired; barrier gives cross-wave visibility.
//      (vmcnt must stay 4: with this stage map, vmcnt(6) would leave
//      A0(t+1)/B0(t+1) possibly unretired at the q3 reads.)
//  (2) Vectorized epilogue via wave-local LDS transpose [16][66] bf16/wave:
//      final bf16 values (identical numerics) written scalar to LDS, read
//      back as 16 contiguous cols/lane, stored 2x dwordx4. 128 scalar
//      global stores -> 16 vector stores; no barriers (wave-local).
//      RESID path keeps the scalar epilogue (f32 resid add precision).
enum { EPI_NONE = 0, EPI_BIAS = 1, EPI_BIAS_RESID = 2, EPI_BIAS_GELU = 3, EPI_QKV = 4 };

#define MM(AF, BF, AH, BH)                                                     \
    __builtin_amdgcn_s_setprio(1);                                             \
    _Pragma("unroll") for (int mi = 0; mi < 4; mi++)                           \
    _Pragma("unroll") for (int ni = 0; ni < 2; ni++)                           \
    _Pragma("unroll") for (int ks = 0; ks < 2; ks++)                           \
        acc[(AH)*4+mi][(BH)*2+ni] = __builtin_amdgcn_mfma_f32_16x16x32_bf16(   \
            AF[mi][ks], BF[ni][ks], acc[(AH)*4+mi][(BH)*2+ni], 0, 0, 0);       \
    __builtin_amdgcn_s_setprio(0);
#define STAGE2(GB, LB)                                                         \
    { load_lds16((GB) + goff0, (LB) + loff0);                                  \
      load_lds16((GB) + goff1, (LB) + loff1); }

// One K-tile: 4 phases, slot parity S literal; reads one phase ahead.
#define KTILE(KT, S)                                                           \
{                                                                              \
    /* q0: stage A1(t+1); bar; read bf1(B1,t); MM(afE,bf0) */                  \
    { const bf16* sp = ((KT) + 1 < NKT)                                        \
          ? A + (size_t)(m0 + 128) * K + (size_t)((KT) + 1) * 64               \
          : (hn ? A + (size_t)(m0n + 128) * K : nullptr);                      \
      if (sp) STAGE2(sp, &Asl[(S) ^ 1][1][0][0]); }                            \
    __builtin_amdgcn_s_barrier();                                              \
    _Pragma("unroll") for (int ni = 0; ni < 2; ni++)                           \
    _Pragma("unroll") for (int ks = 0; ks < 2; ks++)                           \
        bf1[ni][ks] = *(const bf16x8*)(pb[ni][ks] + (S) * 16384 + 8192);       \
    __builtin_amdgcn_sched_barrier(0);                                         \
    MM(afE, bf0, 0, 0)                                                         \
    /* q1: stage B1(t+1); bar; read afO(A1,t); MM(afE,bf1) */                  \
    { const bf16* sp = ((KT) + 1 < NKT)                                        \
          ? W + (size_t)(n0 + 128) * K + (size_t)((KT) + 1) * 64               \
          : (hn ? W + (size_t)(n0n + 128) * K : nullptr);                      \
      if (sp) STAGE2(sp, &Bsl[(S) ^ 1][1][0][0]); }                            \
    __builtin_amdgcn_s_barrier();                                              \
    _Pragma("unroll") for (int mi = 0; mi < 4; mi++)                           \
    _Pragma("unroll") for (int ks = 0; ks < 2; ks++)                           \
        afO[mi][ks] = *(const bf16x8*)(pa[mi][ks] + (S) * 16384 + 8192);       \
    __builtin_amdgcn_sched_barrier(0);                                         \
    MM(afE, bf1, 0, 1)                                                         \
    /* q2: stage A0(t+2); bar; MM(afO,bf1) */                                  \
    { const bf16* sp = ((KT) + 2 < NKT)                                        \
          ? A + (size_t)m0 * K + (size_t)((KT) + 2) * 64                       \
          : (hn ? A + (size_t)m0n * K + (size_t)((KT) + 2 - NKT) * 64          \
               : nullptr);                                                     \
      if (sp) STAGE2(sp, &Asl[(S)][0][0][0]); }                                \
    __builtin_amdgcn_s_barrier();                                              \
    MM(afO, bf1, 1, 1)                                                         \
    /* q3: stage B0(t+2); vmcnt(4); bar; read afE'(A0,t+1); MM(afO,bf0);       \
       read bf0'(B0,t+1) */                                                    \
    { const bf16* sp = ((KT) + 2 < NKT)                                        \
          ? W + (size_t)n0 * K + (size_t)((KT) + 2) * 64                       \
          : (hn ? W + (size_t)n0n * K + (size_t)((KT) + 2 - NKT) * 64          \
               : nullptr);                                                     \
      if (sp) STAGE2(sp, &Bsl[(S)][0][0][0]); }                                \
    if ((KT) + 1 < NKT || hn) {                                                \
        if ((KT) + 2 < NKT || hn) asm volatile("s_waitcnt vmcnt(4)");          \
        else                      asm volatile("s_waitcnt vmcnt(0)");          \
    }                                                                          \
    __builtin_amdgcn_s_barrier();                                              \
    if ((KT) + 1 < NKT || hn) {                                                \
        _Pragma("unroll") for (int mi = 0; mi < 4; mi++)                       \
        _Pragma("unroll") for (int ks = 0; ks < 2; ks++)                       \
            afE[mi][ks] = *(const bf16x8*)(pa[mi][ks] + ((S) ^ 1) * 16384);    \
    }                                                                          \
    __builtin_amdgcn_sched_barrier(0);                                         \
    MM(afO, bf0, 1, 0)                                                         \
    if ((KT) + 1 < NKT || hn) {                                                \
        _Pragma("unroll") for (int ni = 0; ni < 2; ni++)                       \
        _Pragma("unroll") for (int ks = 0; ks < 2; ks++)                       \
            bf0[ni][ks] = *(const bf16x8*)(pb[ni][ks] + ((S) ^ 1) * 16384);    \
    }                                                                          \
    __builtin_amdgcn_sched_barrier(0);                                         \
}

template<typename OutT, int EPI>
__global__ __launch_bounds__(512, 2) void gemm256(
    const bf16* __restrict__ A, const bf16* __restrict__ W,
    const bf16* __restrict__ bias, const void* __restrict__ resid,
    const int* __restrict__ flag,
    OutT* __restrict__ Cout, bf16* __restrict__ Cout2, int M, int Nn, int K)
{
    __shared__ bf16 Asl[2][2][128][64];   // [slot][half][row][k]  64 KiB
    __shared__ bf16 Bsl[2][2][128][64];   // 64 KiB
    __shared__ bf16 EpiL[8][16][66];      // per-wave epilogue transpose, 16.5 KiB
    const int t = threadIdx.x;
    const int wv = t >> 6, lane = t & 63;
    const int quad = lane >> 4, l16 = lane & 15;
    const int wm = wv >> 2, wn = wv & 3;          // wave tile: 128 rows x 64 cols
    const int Nt = Nn >> 8;
    const int total = (M >> 8) * Nt;
    const int G = gridDim.x;
    const int NKT = K >> 6;                        // BK=64 K-tiles (even)

    // hoisted swizzled LDS read pointers (12 regs); slot/half via offset imm
    const bf16* pa[4][2];
    const bf16* pb[2][2];
#pragma unroll
    for (int mi = 0; mi < 4; mi++) {
        int row = wm * 64 + mi * 16 + l16;
#pragma unroll
        for (int ks = 0; ks < 2; ks++)
            pa[mi][ks] = &Asl[0][0][0][0] + row * 64 +
                         ((ks * 32 + quad * 8) ^ ((row & 7) << 3));
    }
#pragma unroll
    for (int ni = 0; ni < 2; ni++) {
        int row = wn * 32 + ni * 16 + l16;
#pragma unroll
        for (int ks = 0; ks < 2; ks++)
            pb[ni][ks] = &Bsl[0][0][0][0] + row * 64 +
                         ((ks * 32 + quad * 8) ^ ((row & 7) << 3));
    }

    // loop-invariant stage addressing (16B chunk c: row=c>>3, swizzled slot)
    const int c0 = t, c1 = 512 + t;
    const int r0 = c0 >> 3, r1 = c1 >> 3;
    const size_t goff0 = (size_t)r0 * K + (size_t)(((c0 & 7) ^ (r0 & 7)) * 8);
    const size_t goff1 = (size_t)r1 * K + (size_t)(((c1 & 7) ^ (r1 & 7)) * 8);
    const int loff0 = c0 * 8, loff1 = c1 * 8;

    int id = blockIdx.x;
    if (id >= total) return;
    int m0 = (((id >> 3) / Nt) * 8 + (id & 7)) * 256;
    int n0 = ((id >> 3) % Nt) * 256;

    // ---- prologue: K-tile 0 fully + first halves of K-tile 1 ----
    STAGE2(A + (size_t)m0 * K,         &Asl[0][0][0][0]);  // A0(0)
    STAGE2(W + (size_t)n0 * K,         &Bsl[0][0][0][0]);  // B0(0)
    STAGE2(A + (size_t)(m0 + 128) * K, &Asl[0][1][0][0]);  // A1(0)
    STAGE2(W + (size_t)(n0 + 128) * K, &Bsl[0][1][0][0]);  // B1(0)
    STAGE2(A + (size_t)m0 * K + 64,    &Asl[1][0][0][0]);  // A0(1)
    STAGE2(W + (size_t)n0 * K + 64,    &Bsl[1][0][0][0]);  // B0(1)
    asm volatile("s_waitcnt vmcnt(4)");   // K-tile 0 resident; A0(1),B0(1) in flight
    __builtin_amdgcn_s_barrier();

    bf16x8 afE[4][2], afO[4][2], bf0[2][2], bf1[2][2];
#pragma unroll
    for (int mi = 0; mi < 4; mi++)
#pragma unroll
        for (int ks = 0; ks < 2; ks++)
            afE[mi][ks] = *(const bf16x8*)(pa[mi][ks]);          // A0(0)
#pragma unroll
    for (int ni = 0; ni < 2; ni++)
#pragma unroll
        for (int ks = 0; ks < 2; ks++)
            bf0[ni][ks] = *(const bf16x8*)(pb[ni][ks]);          // B0(0)

    for (;;) {
        const int idn = id + G;
        const bool hn = idn < total;
        int m0n = 0, n0n = 0;
        if (hn) {
            m0n = (((idn >> 3) / Nt) * 8 + (idn & 7)) * 256;
            n0n = ((idn >> 3) % Nt) * 256;
        }

        floatx4 acc[8][4] = {};

        for (int kt = 0; kt < NKT; kt += 2) {
            KTILE(kt, 0)
            KTILE(kt + 1, 1)
        }

        // ---- epilogue (next tile's K-tile 0 resident; afE/bf0 preloaded) ----
        if constexpr (EPI != EPI_BIAS_RESID) {
            // vectorized: wave-local LDS transpose, identical numerics
            bf16* epi = &EpiL[wv][0][0];
            const int rl = lane >> 2, cg = lane & 3;
#pragma unroll
            for (int mg = 0; mg < 8; mg++) {
#pragma unroll
                for (int ng = 0; ng < 4; ng++) {
                    int col = n0 + (ng >> 1) * 128 + wn * 32 + (ng & 1) * 16 + l16;
                    float bv = (EPI == EPI_BIAS || EPI == EPI_BIAS_GELU)
                               ? (float)bias[col] : 0.f;
                    int cc2 = (ng >> 1) * 32 + (ng & 1) * 16 + l16;
#pragma unroll
                    for (int r = 0; r < 4; r++) {
                        float v = acc[mg][ng][r] + bv;
                        if (EPI == EPI_BIAS_GELU) v = gelu_fast(v);
                        epi[(quad * 4 + r) * 66 + cc2] = (bf16)v;
                    }
                }
                // wave-local readback (compiler inserts lgkm waits)
                bf16x8 v0 = *(const bf16x8*)(epi + rl * 66 + cg * 16);
                bf16x8 v1 = *(const bf16x8*)(epi + rl * 66 + cg * 16 + 8);
                int rowg = m0 + (mg >> 2) * 128 + wm * 64 + (mg & 3) * 16 + rl;
                int colg = n0 + (cg >> 1) * 128 + wn * 32 + (cg & 1) * 16;
                bf16* dst;
                if (EPI == EPI_QKV && colg >= 512)
                    dst = Cout2 + (size_t)rowg * 1024 + (colg - 512);
                else if (EPI == EPI_QKV)
                    dst = (bf16*)(void*)Cout + (size_t)rowg * 512 + colg;
                else
                    dst = (bf16*)(void*)Cout + (size_t)rowg * (size_t)Nn + colg;
                *(bf16x8*)dst = v0;
                *(bf16x8*)(dst + 8) = v1;
            }
        } else {
            // scalar path (resid add in f32 before single rounding)
            bool isbf = (*flag != 0);
#pragma unroll
            for (int mg = 0; mg < 8; mg++) {
                int rowg = m0 + (mg >> 2) * 128 + wm * 64 + (mg & 3) * 16 + quad * 4;
#pragma unroll
                for (int ng = 0; ng < 4; ng++) {
                    int col = n0 + (ng >> 1) * 128 + wn * 32 + (ng & 1) * 16 + l16;
                    float bv = (float)bias[col];
#pragma unroll
                    for (int r = 0; r < 4; r++) {
                        size_t idx = (size_t)(rowg + r) * (size_t)Nn + col;
                        float v = acc[mg][ng][r] + bv;
                        float rres = isbf ? (float)((const bf16*)resid)[idx]
                                          : ((const float*)resid)[idx];
                        v += rres;
                        Cout[idx] = (OutT)v;
                    }
                }
            }
        }

        if (!hn) break;
        id = idn; m0 = m0n; n0 = n0n;
    }
}

// ====================== attention (MFMA) ===================================
// grid (8 slices, 64 bh): partial[(bh*8+s)*4096 + d*64+e] over 512 tokens
__global__ __launch_bounds__(256) void attn_logits_mfma(
    const bf16* __restrict__ kv, float* __restrict__ partial)
{
    __shared__ bf16 Kt[64][136];
    __shared__ bf16 Vt[64][136];
    int s = blockIdx.x, bh = blockIdx.y, b = bh >> 3, h = bh & 7;
    int t = threadIdx.x, wave = t >> 6, lane = t & 63;
    int quad = lane >> 4, l16 = lane & 15;
    floatx4 acc[4] = {};
    for (int c = 0; c < 4; c++) {
        int n0 = s * 512 + c * 128;
        {
            int isv = t >> 7;
            int r   = t & 127;
            const bf16* gp = &kv[((size_t)b * N_ + n0 + r) * 1024 + h * 64 + isv * 512];
            bf16x8 rowv[8];
#pragma unroll
            for (int u = 0; u < 8; u++) rowv[u] = *(const bf16x8*)(gp + u * 8);
            bf16 (*dst)[136] = isv ? Vt : Kt;
#pragma unroll
            for (int u = 0; u < 8; u++)
#pragma unroll
                for (int jj = 0; jj < 8; jj++)
                    dst[u * 8 + jj][r] = rowv[u][jj];
        }
        __syncthreads();
#pragma unroll
        for (int ks = 0; ks < 4; ks++) {
            bf16x8 af = *(const bf16x8*)&Kt[wave * 16 + l16][ks * 32 + quad * 8];
#pragma unroll
            for (int ni = 0; ni < 4; ni++) {
                bf16x8 bfv = *(const bf16x8*)&Vt[ni * 16 + l16][ks * 32 + quad * 8];
                acc[ni] = __builtin_amdgcn_mfma_f32_16x16x32_bf16(af, bfv, acc[ni], 0, 0, 0);
            }
        }
        __syncthreads();
    }
    float* p = partial + ((size_t)bh * 8 + s) * 4096;
#pragma unroll
    for (int ni = 0; ni < 4; ni++)
#pragma unroll
        for (int r = 0; r < 4; r++)
            p[(wave * 16 + quad * 4 + r) * 64 + ni * 16 + l16] = acc[ni][r];
}

// softmax: grid (4, 64); block handles 16 d rows (wave*4 + r)
__global__ __launch_bounds__(256) void attn_softmax_kernel(
    const float* __restrict__ partial, bf16* __restrict__ attnb)
{
    int bh = blockIdx.y;
    int wave = threadIdx.x >> 6, lane = threadIdx.x & 63;
    for (int r = 0; r < 4; r++) {
        int d = blockIdx.x * 16 + wave * 4 + r;
        float v = 0.f;
#pragma unroll
        for (int s = 0; s < 8; s++) v += partial[((size_t)bh*8 + s)*4096 + d*64 + lane];
        v *= SCALE_;
        float m = v;
#pragma unroll
        for (int off = 32; off; off >>= 1) m = fmaxf(m, __shfl_xor(m, off));
        float p = expf(v - m);
        float sum = p;
#pragma unroll
        for (int off = 32; off; off >>= 1) sum += __shfl_xor(sum, off);
        attnb[(size_t)bh*4096 + d*64 + lane] = (bf16)(p / sum);
    }
}

// apply: outT[n][h*64+d] = sum_e attn[d][e] * q[n][h*64+e]
__global__ __launch_bounds__(256) void attn_apply_mfma(
    const bf16* __restrict__ q, const bf16* __restrict__ attnb,
    bf16* __restrict__ outT)
{
    int bh = blockIdx.y, b = bh >> 3, h = bh & 7;
    int t = threadIdx.x, wave = t >> 6, lane = t & 63;
    int quad = lane >> 4, l16 = lane & 15;
    int nbase = blockIdx.x * 256 + wave * 64;
    bf16x8 bfrag[4][2];
#pragma unroll
    for (int di = 0; di < 4; di++)
#pragma unroll
        for (int ks = 0; ks < 2; ks++)
            bfrag[di][ks] = *(const bf16x8*)&attnb[(size_t)bh*4096 + (di*16 + l16)*64 + ks*32 + quad*8];
    floatx4 acc[4][4] = {};
#pragma unroll
    for (int mi = 0; mi < 4; mi++) {
#pragma unroll
        for (int ks = 0; ks < 2; ks++) {
            bf16x8 af = *(const bf16x8*)&q[((size_t)b*N_ + nbase + mi*16 + l16)*512 + h*64 + ks*32 + quad*8];
#pragma unroll
            for (int di = 0; di < 4; di++)
                acc[mi][di] = __builtin_amdgcn_mfma_f32_16x16x32_bf16(af, bfrag[di][ks], acc[mi][di], 0, 0, 0);
        }
    }
#pragma unroll
    for (int mi = 0; mi < 4; mi++)
#pragma unroll
        for (int di = 0; di < 4; di++)
#pragma unroll
            for (int r = 0; r < 4; r++)
                outT[((size_t)b*N_ + nbase + mi*16 + quad*4 + r)*512 + h*64 + di*16 + l16] =
                    (bf16)acc[mi][di][r];
}

// ====================== ECA ================================================
__global__ __launch_bounds__(256) void pooled_kernel(
    const bf16* __restrict__ y, float* __restrict__ pooled)
{
    int bc = blockIdx.x;
    const bf16* p = y + (size_t)bc * 4096 + threadIdx.x * 16;
    float s = 0.f;
#pragma unroll
    for (int i = 0; i < 2; i++) {
        bf16x8 v = *(const bf16x8*)(p + i*8);
#pragma unroll
        for (int j = 0; j < 8; j++) s += (float)v[j];
    }
#pragma unroll
    for (int off = 32; off; off >>= 1) s += __shfl_xor(s, off);
    __shared__ float red[4];
    if ((threadIdx.x & 63) == 0) red[threadIdx.x >> 6] = s;
    __syncthreads();
    if (threadIdx.x == 0)
        pooled[bc] = (red[0] + red[1] + red[2] + red[3]) * (1.f/4096.f);
}

__global__ void gate_kernel(const float* __restrict__ pooled,
                            const bf16* __restrict__ eca_w, float* __restrict__ gate1)
{
    int c = threadIdx.x, b = blockIdx.x;
    float w0 = (float)eca_w[0], w1 = (float)eca_w[1], w2 = (float)eca_w[2];
    const float* p = pooled + b * 512;
    float conv = w1 * p[c];
    if (c > 0)   conv += w0 * p[c-1];
    if (c < 511) conv += w2 * p[c+1];
    float g = 1.f / (1.f + expf(-conv));
    gate1[b * 512 + c] = 1.f + g;
}

// ------- final, layout B: RMW fp32 d_out -------
__global__ __launch_bounds__(256) void final_rmw(
    const bf16* __restrict__ y, const float* __restrict__ gate1,
    float* __restrict__ out)
{
    int b = blockIdx.z, c0 = blockIdx.y * 64, n0 = blockIdx.x * 64;
    __shared__ float ytile[64][65];
    int t = threadIdx.x;
#pragma unroll
    for (int i = 0; i < 2; i++) {
        int chunk = t * 2 + i;
        int ci = chunk >> 3, nj = (chunk & 7) * 8;
        bf16x8 v = *(const bf16x8*)&y[(size_t)b * ((size_t)N_*C_) + (size_t)(c0+ci) * 4096 + n0 + nj];
#pragma unroll
        for (int j = 0; j < 8; j++) ytile[ci][nj+j] = (float)v[j];
    }
    __syncthreads();
    int cc = t & 63, nb = t >> 6;
    float g = gate1[b * 512 + c0 + cc];
    for (int p = 0; p < 16; p++) {
        int nr = p * 4 + nb;
        size_t idx = ((size_t)b * N_ + n0 + nr) * C_ + c0 + cc;
        out[idx] = out[idx] + g * ytile[cc][nr];
    }
}

// ------- final, layout A: read bf16 x2, write fresh fp32 -------
__global__ __launch_bounds__(256) void final_fresh(
    const bf16* __restrict__ y, const bf16* __restrict__ x2b,
    const float* __restrict__ gate1, float* __restrict__ out)
{
    int b = blockIdx.z, c0 = blockIdx.y * 64, n0 = blockIdx.x * 64;
    __shared__ float ytile[64][65];
    int t = threadIdx.x;
#pragma unroll
    for (int i = 0; i < 2; i++) {
        int chunk = t * 2 + i;
        int ci = chunk >> 3, nj = (chunk & 7) * 8;
        bf16x8 v = *(const bf16x8*)&y[(size_t)b * ((size_t)N_*C_) + (size_t)(c0+ci) * 4096 + n0 + nj];
#pragma unroll
        for (int j = 0; j < 8; j++) ytile[ci][nj+j] = (float)v[j];
    }
    __syncthreads();
    int cc = t & 63, nb = t >> 6;
    float g = gate1[b * 512 + c0 + cc];
    for (int p = 0; p < 16; p++) {
        int nr = p * 4 + nb;
        size_t idx = ((size_t)b * N_ + n0 + nr) * C_ + c0 + cc;
        out[idx] = (float)x2b[idx] + g * ytile[cc][nr];
    }
}

// ====================== launcher ===========================================
extern "C" void kernel_launch(void* const* d_in, const int* in_sizes, int n_in,
                              void* d_out, int out_size, void* d_ws, size_t ws_size,
                              hipStream_t stream)
{
    float* outf = (float*)d_out;
    bf16*  outb = (bf16*)d_out;
    char* ws = (char*)d_ws;

    int*   flag    = (int*)ws;
    float* pooled  = (float*)(ws + 4096);
    float* gate1   = (float*)(ws + 20480);
    bf16* ln1_w = (bf16*)(ws + 65536);
    bf16* ln1_b = (bf16*)(ws + 67584);
    bf16* ln2_w = (bf16*)(ws + 69632);
    bf16* ln2_b = (bf16*)(ws + 71680);
    bf16* proj_b= (bf16*)(ws + 73728);
    bf16* fc2_b = (bf16*)(ws + 75776);
    bf16* eca_w = (bf16*)(ws + 77824);
    bf16* fc1_b = (bf16*)(ws + 81920);
    bf16* qkv_w = (bf16*)(ws + ((size_t)1 << 20));
    bf16* proj_w= (bf16*)(ws + (size_t)2621440);
    bf16* fc1_w = (bf16*)(ws + ((size_t)3 << 20));
    bf16* fc2_w = (bf16*)(ws + ((size_t)5 << 20));
    float* partial = (float*)(ws + ((size_t)7  << 20));
    bf16*  attnb   = (bf16*)(ws + ((size_t)15 << 20));
    bf16*  T1      = (bf16*)(ws + ((size_t)16 << 20));
    bf16*  kvbuf   = (bf16*)(ws + ((size_t)48 << 20));
    bf16*  hbuf    = kvbuf;
    bf16*  x2b     = (bf16*)(ws + ((size_t)176 << 20));

    const bool fat = ws_size >= ((size_t)212 << 20);

    // 0. sniff input dtype
    sniff_kernel<<<1, 256, 0, stream>>>((const unsigned int*)d_in[0], flag);

    // 1. convert params to bf16
    ConvArgs ca;
    const int   srcidx[12] = { 1, 2, 6, 7, 5, 11, 12, 9, 3, 4, 8, 10 };
    const unsigned offs[12] = { 65536, 67584, 69632, 71680, 73728, 75776, 77824, 81920,
                                1u<<20, 2621440u, 3u<<20, 5u<<20 };
    for (int i = 0; i < 12; i++) {
        ca.src[i] = d_in[srcidx[i]];
        ca.dstoff[i] = offs[i];
        ca.n[i] = in_sizes[srcidx[i]];
    }
    convert_params<<<dim3(512, 12), 256, 0, stream>>>(ca, ws, flag);

    // 2. LN1 -> T1
    ln_dyn_kernel<<<BN_/4, 256, 0, stream>>>(d_in[0], ln1_w, ln1_b, T1, flag);

    // 3. QKV GEMM: q (bf16) -> d_out, kv -> kvbuf  (768 tiles, 3/block)
    gemm256<bf16, EPI_QKV><<<256, 512, 0, stream>>>(
        T1, qkv_w, nullptr, nullptr, flag, outb, kvbuf, BN_, 1536, 512);

    // 4. attention
    attn_logits_mfma<<<dim3(8, 64), 256, 0, stream>>>(kvbuf, partial);
    attn_softmax_kernel<<<dim3(4, 64), 256, 0, stream>>>(partial, attnb);
    attn_apply_mfma<<<dim3(16, 64), 256, 0, stream>>>(outb, attnb, T1);

    if (fat) {
        // 5. proj + bias + residual(x) -> x2b (bf16)   (256 tiles, 1/block)
        gemm256<bf16, EPI_BIAS_RESID><<<256, 512, 0, stream>>>(
            T1, proj_w, proj_b, d_in[0], flag, x2b, nullptr, BN_, 512, 512);
        // 6. LN2: x2b -> T1
        ln_b16_kernel<<<BN_/4, 256, 0, stream>>>(x2b, ln2_w, ln2_b, T1);
        // 7. FC1 full: T1 -> hbuf (128MB)  (1024 tiles, 4/block)
        gemm256<bf16, EPI_BIAS_GELU><<<256, 512, 0, stream>>>(
            T1, fc1_w, fc1_b, nullptr, flag, hbuf, nullptr, BN_, 2048, 512);
        // 8. FC2 full: hbuf -> T1 (y)      (256 tiles, 1/block)
        gemm256<bf16, EPI_BIAS><<<256, 512, 0, stream>>>(
            hbuf, fc2_w, fc2_b, nullptr, flag, T1, nullptr, BN_, 512, 2048);
        // 9. ECA
        pooled_kernel<<<4096, 256, 0, stream>>>(T1, pooled);
        gate_kernel<<<8, 512, 0, stream>>>(pooled, eca_w, gate1);
        // 10. final: fp32 out = x2b + gate*y  (no RMW)
        final_fresh<<<dim3(64, 8, 8), 256, 0, stream>>>(T1, x2b, gate1, outf);
    } else {
        // 5. proj + bias + residual(x) -> x2 (fp32) in d_out
        gemm256<float, EPI_BIAS_RESID><<<256, 512, 0, stream>>>(
            T1, proj_w, proj_b, d_in[0], flag, outf, nullptr, BN_, 512, 512);
        // 6. LN2: d_out fp32 -> T1
        ln_f32_kernel<<<BN_/4, 256, 0, stream>>>(outf, ln2_w, ln2_b, T1);
        // 7-8. chunked FC (hbuf 64MB)
        for (int ch = 0; ch < 2; ch++) {
            bf16* Tch = T1 + (size_t)ch * 16384 * 512;
            gemm256<bf16, EPI_BIAS_GELU><<<256, 512, 0, stream>>>(
                Tch, fc1_w, fc1_b, nullptr, flag, hbuf, nullptr, 16384, 2048, 512);
            gemm256<bf16, EPI_BIAS><<<128, 512, 0, stream>>>(
                hbuf, fc2_w, fc2_b, nullptr, flag, Tch, nullptr, 16384, 512, 2048);
        }
        // 9. ECA
        pooled_kernel<<<4096, 256, 0, stream>>>(T1, pooled);
        gate_kernel<<<8, 512, 0, stream>>>(pooled, eca_w, gate1);
        // 10. final RMW on fp32 d_out
        final_rmw<<<dim3(64, 8, 8), 256, 0, stream>>>(T1, gate1, outf);
    }
}

// Round 7
// 495.551 us; speedup vs baseline: 1.0860x; 1.0354x over previous
//
#include <hip/hip_runtime.h>
#include <hip/hip_bf16.h>

typedef __bf16 bf16;
typedef __bf16 bf16x8 __attribute__((ext_vector_type(8)));
typedef float floatx4 __attribute__((ext_vector_type(4)));

#define B_    8
#define N_    4096
#define C_    512
#define BN_   32768      // B_*N_
#define HID_  2048
#define SCALE_ 0.125f    // 64^-0.5

// async 16B global -> LDS (m97 lever)
__device__ __forceinline__ void load_lds16(const void* g, void* l) {
    __builtin_amdgcn_global_load_lds(
        (const __attribute__((address_space(1))) void*)g,
        (__attribute__((address_space(3))) void*)l, 16, 0, 0);
}

// fast exact-tanh GELU: v * sigmoid(1.5957691*(v+0.044715 v^3))
__device__ __forceinline__ float gelu_fast(float v) {
    float c = fmaf(v * v, 0.044715f, 1.0f) * v;
    float e = __builtin_amdgcn_exp2f(-2.3022082f * c);
    return v * __builtin_amdgcn_rcpf(1.0f + e);
}

// ====================== dtype sniff ========================================
__global__ void sniff_kernel(const unsigned int* __restrict__ xw, int* __restrict__ flag)
{
    int t = threadIdx.x;
    int votes = 0;
#pragma unroll
    for (int i = 0; i < 4; i++) {
        unsigned w = xw[t * 4 + i];
        if (w == 0u) continue;
        unsigned a = w & 0xFFFFu;
        unsigned e = (a >> 7) & 0xFFu;
        if (a != 0u && e >= 110u && e <= 135u) votes++; else votes--;
    }
#pragma unroll
    for (int off = 32; off; off >>= 1) votes += __shfl_xor(votes, off);
    __shared__ int s[4];
    if ((t & 63) == 0) s[t >> 6] = votes;
    __syncthreads();
    if (t == 0) *flag = (s[0] + s[1] + s[2] + s[3]) > 0 ? 1 : 0;  // 1 = bf16
}

// ====================== param conversion ===================================
struct ConvArgs {
    const void* src[12];
    unsigned    dstoff[12];
    int         n[12];
};

__global__ __launch_bounds__(256) void convert_params(
    ConvArgs args, char* __restrict__ ws, const int* __restrict__ flag)
{
    int seg = blockIdx.y;
    int n = args.n[seg];
    int base = blockIdx.x * 2048;
    if (base >= n) return;
    bf16* dst = (bf16*)(ws + args.dstoff[seg]);
    const void* src = args.src[seg];
    bool isbf = (*flag != 0);
#pragma unroll
    for (int j = 0; j < 8; j++) {
        int idx = base + threadIdx.x + j * 256;
        if (idx < n) {
            float v = isbf ? (float)((const bf16*)src)[idx]
                           : ((const float*)src)[idx];
            dst[idx] = (bf16)v;
        }
    }
}

// ====================== LayerNorm variants =================================
__device__ __forceinline__ void ln_core(float f[8], const bf16* w, const bf16* b,
                                        int lane, bf16* outp)
{
    float s = 0.f, sq = 0.f;
#pragma unroll
    for (int j = 0; j < 8; j++) { s += f[j]; sq += f[j]*f[j]; }
#pragma unroll
    for (int off = 32; off; off >>= 1) { s += __shfl_xor(s, off); sq += __shfl_xor(sq, off); }
    float mean = s * (1.f/512.f);
    float var  = sq * (1.f/512.f) - mean*mean;
    float inv  = rsqrtf(var + 1e-5f);
    bf16x8 wv = *(const bf16x8*)(w + lane*8);
    bf16x8 bv = *(const bf16x8*)(b + lane*8);
    bf16x8 o;
#pragma unroll
    for (int j = 0; j < 8; j++) o[j] = (bf16)((f[j]-mean)*inv*(float)wv[j] + (float)bv[j]);
    *(bf16x8*)outp = o;
}

__global__ __launch_bounds__(256) void ln_dyn_kernel(
    const void* __restrict__ xv, const bf16* __restrict__ w,
    const bf16* __restrict__ b, bf16* __restrict__ out, const int* __restrict__ flag)
{
    int wave = threadIdx.x >> 6, lane = threadIdx.x & 63;
    size_t row = (size_t)blockIdx.x * 4 + wave;
    float f[8];
    if (*flag) {
        bf16x8 v = *(const bf16x8*)((const bf16*)xv + row * C_ + lane * 8);
#pragma unroll
        for (int j = 0; j < 8; j++) f[j] = (float)v[j];
    } else {
        const float4* p = (const float4*)((const float*)xv + row * C_ + lane * 8);
        float4 v0 = p[0], v1 = p[1];
        f[0]=v0.x; f[1]=v0.y; f[2]=v0.z; f[3]=v0.w;
        f[4]=v1.x; f[5]=v1.y; f[6]=v1.z; f[7]=v1.w;
    }
    ln_core(f, w, b, lane, out + row * C_ + lane*8);
}

__global__ __launch_bounds__(256) void ln_b16_kernel(
    const bf16* __restrict__ x, const bf16* __restrict__ w,
    const bf16* __restrict__ b, bf16* __restrict__ out)
{
    int wave = threadIdx.x >> 6, lane = threadIdx.x & 63;
    size_t row = (size_t)blockIdx.x * 4 + wave;
    bf16x8 v = *(const bf16x8*)(x + row * C_ + lane * 8);
    float f[8];
#pragma unroll
    for (int j = 0; j < 8; j++) f[j] = (float)v[j];
    ln_core(f, w, b, lane, out + row * C_ + lane*8);
}

__global__ __launch_bounds__(256) void ln_f32_kernel(
    const float* __restrict__ x, const bf16* __restrict__ w,
    const bf16* __restrict__ b, bf16* __restrict__ out)
{
    int wave = threadIdx.x >> 6, lane = threadIdx.x & 63;
    size_t row = (size_t)blockIdx.x * 4 + wave;
    const float4* p = (const float4*)(x + row * C_ + lane * 8);
    float4 v0 = p[0], v1 = p[1];
    float f[8] = { v0.x, v0.y, v0.z, v0.w, v1.x, v1.y, v1.z, v1.w };
    ln_core(f, w, b, lane, out + row * C_ + lane*8);
}

// ====================== 128x128 MFMA GEMM (m97-structure, 3 blocks/CU) =====
// R6 post-mortem: 6 rounds of intra-block pipelining on the 256²/1-block-CU
// structure all land 22-30% MfmaUtil; the guide's m97/m103 structure (128²,
// simple 2-barrier drain loop, ~3 resident blocks/CU) measures 36% — the
// overlap comes from INDEPENDENT barrier domains, not intra-block scheduling.
// This kernel = m97 structure + the three proven fixes:
//  - conflict-free XOR swizzle: byte ^= (row&7)<<4, applied as pre-swizzled
//    global_load_lds SOURCE + swizzled hoisted ds_read pointers (rule 21)
//  - gelu_fast epilogue (erff was ~30 VALU/value)
//  - XCD-grouped block id (all grids %8 == 0)
// Geometry: 256 thr = 4 waves (2M x 2N), wave tile 64x64, BK=64,
// LDS 32 KiB (single-buffered), __launch_bounds__(256,3) -> 3 blocks/CU.
// No persistence, no manual vmcnt: __syncthreads' implicit vmcnt(0) drain
// per K-tile is covered by the sibling blocks' compute.
enum { EPI_NONE = 0, EPI_BIAS = 1, EPI_BIAS_RESID = 2, EPI_BIAS_GELU = 3, EPI_QKV = 4 };

template<typename OutT, int EPI>
__global__ __launch_bounds__(256, 3) void gemm128(
    const bf16* __restrict__ A, const bf16* __restrict__ W,
    const bf16* __restrict__ bias, const void* __restrict__ resid,
    const int* __restrict__ flag,
    OutT* __restrict__ Cout, bf16* __restrict__ Cout2, int M, int Nn, int K)
{
    __shared__ bf16 As[128][64];   // 16 KiB
    __shared__ bf16 Bs[128][64];   // 16 KiB
    const int t = threadIdx.x;
    const int wv = t >> 6, lane = t & 63;
    const int quad = lane >> 4, l16 = lane & 15;
    const int wm = (wv & 1) * 64, wn = (wv >> 1) * 64;   // wave tile 64x64
    const int Nt = Nn >> 7;
    const int id = blockIdx.x;
    const int xcd = id & 7, j = id >> 3;
    const int m0 = ((j / Nt) * 8 + xcd) * 128;
    const int n0 = (j % Nt) * 128;
    const int NKT = K >> 6;

    // hoisted swizzled LDS read pointers (R5 lever; loop-invariant)
    const bf16* pa[4][2];
    const bf16* pb[4][2];
#pragma unroll
    for (int mi = 0; mi < 4; mi++) {
        int row = wm + mi * 16 + l16;
#pragma unroll
        for (int ks = 0; ks < 2; ks++)
            pa[mi][ks] = &As[0][0] + row * 64 +
                         ((ks * 32 + quad * 8) ^ ((row & 7) << 3));
    }
#pragma unroll
    for (int ni = 0; ni < 4; ni++) {
        int row = wn + ni * 16 + l16;
#pragma unroll
        for (int ks = 0; ks < 2; ks++)
            pb[ni][ks] = &Bs[0][0] + row * 64 +
                         ((ks * 32 + quad * 8) ^ ((row & 7) << 3));
    }

    // stage addressing: 4 16B-chunks per thread per tile (1024 chunks/tile)
    // chunk c: row = c>>3, phys slot c&7, source col = (c&7)^(row&7)
    size_t goff[4]; int loff[4];
#pragma unroll
    for (int i = 0; i < 4; i++) {
        int c = i * 256 + t, r = c >> 3;
        goff[i] = (size_t)r * K + (size_t)(((c & 7) ^ (r & 7)) * 8);
        loff[i] = c * 8;
    }

    const bf16* aA = A + (size_t)m0 * K;
    const bf16* aB = W + (size_t)n0 * K;

    floatx4 acc[4][4] = {};
    for (int kt = 0; kt < NKT; ++kt) {
#pragma unroll
        for (int i = 0; i < 4; i++) load_lds16(aA + goff[i], &As[0][0] + loff[i]);
#pragma unroll
        for (int i = 0; i < 4; i++) load_lds16(aB + goff[i], &Bs[0][0] + loff[i]);
        __syncthreads();                 // implicit vmcnt(0)+lgkmcnt(0) drain
        bf16x8 af[4][2];
#pragma unroll
        for (int mi = 0; mi < 4; mi++)
#pragma unroll
            for (int ks = 0; ks < 2; ks++)
                af[mi][ks] = *(const bf16x8*)pa[mi][ks];
#pragma unroll
        for (int ni = 0; ni < 4; ni++) {
            bf16x8 b0 = *(const bf16x8*)pb[ni][0];
            bf16x8 b1 = *(const bf16x8*)pb[ni][1];
#pragma unroll
            for (int mi = 0; mi < 4; mi++) {
                acc[mi][ni] = __builtin_amdgcn_mfma_f32_16x16x32_bf16(
                    af[mi][0], b0, acc[mi][ni], 0, 0, 0);
                acc[mi][ni] = __builtin_amdgcn_mfma_f32_16x16x32_bf16(
                    af[mi][1], b1, acc[mi][ni], 0, 0, 0);
            }
        }
        __syncthreads();                 // protect LDS for next stage (WAR)
        aA += 64; aB += 64;
    }

    // ---- epilogue (R0-proven scalar form) ----
    size_t ldc = (size_t)Nn; int csub = 0; bool to2 = false;
    if (EPI == EPI_QKV) {
        if (n0 >= 512) { to2 = true; ldc = 1024; csub = 512; }
        else           { ldc = 512; }
    }
    bool isbf = false;
    if (EPI == EPI_BIAS_RESID) isbf = (*flag != 0);

#pragma unroll
    for (int mi = 0; mi < 4; mi++) {
#pragma unroll
        for (int ni = 0; ni < 4; ni++) {
            int col = n0 + wn + ni * 16 + l16;
            float bv = (EPI == EPI_BIAS || EPI == EPI_BIAS_RESID || EPI == EPI_BIAS_GELU)
                       ? (float)bias[col] : 0.f;
#pragma unroll
            for (int r = 0; r < 4; r++) {
                int rowg = m0 + wm + mi * 16 + quad * 4 + r;
                size_t idx = (size_t)rowg * ldc + (col - csub);
                float v = acc[mi][ni][r] + bv;
                if (EPI == EPI_BIAS_RESID) {
                    float rres = isbf ? (float)((const bf16*)resid)[idx]
                                      : ((const float*)resid)[idx];
                    v += rres;
                }
                if (EPI == EPI_BIAS_GELU)  v = gelu_fast(v);
                if (EPI == EPI_QKV && to2) Cout2[idx] = (bf16)v;
                else                       Cout[idx]  = (OutT)v;
            }
        }
    }
}

// ====================== attention (MFMA) ===================================
// grid (8 slices, 64 bh): partial[(bh*8+s)*4096 + d*64+e] over 512 tokens
__global__ __launch_bounds__(256) void attn_logits_mfma(
    const bf16* __restrict__ kv, float* __restrict__ partial)
{
    __shared__ bf16 Kt[64][136];
    __shared__ bf16 Vt[64][136];
    int s = blockIdx.x, bh = blockIdx.y, b = bh >> 3, h = bh & 7;
    int t = threadIdx.x, wave = t >> 6, lane = t & 63;
    int quad = lane >> 4, l16 = lane & 15;
    floatx4 acc[4] = {};
    for (int c = 0; c < 4; c++) {
        int n0 = s * 512 + c * 128;
        {
            int isv = t >> 7;
            int r   = t & 127;
            const bf16* gp = &kv[((size_t)b * N_ + n0 + r) * 1024 + h * 64 + isv * 512];
            bf16x8 rowv[8];
#pragma unroll
            for (int u = 0; u < 8; u++) rowv[u] = *(const bf16x8*)(gp + u * 8);
            bf16 (*dst)[136] = isv ? Vt : Kt;
#pragma unroll
            for (int u = 0; u < 8; u++)
#pragma unroll
                for (int jj = 0; jj < 8; jj++)
                    dst[u * 8 + jj][r] = rowv[u][jj];
        }
        __syncthreads();
#pragma unroll
        for (int ks = 0; ks < 4; ks++) {
            bf16x8 af = *(const bf16x8*)&Kt[wave * 16 + l16][ks * 32 + quad * 8];
#pragma unroll
            for (int ni = 0; ni < 4; ni++) {
                bf16x8 bfv = *(const bf16x8*)&Vt[ni * 16 + l16][ks * 32 + quad * 8];
                acc[ni] = __builtin_amdgcn_mfma_f32_16x16x32_bf16(af, bfv, acc[ni], 0, 0, 0);
            }
        }
        __syncthreads();
    }
    float* p = partial + ((size_t)bh * 8 + s) * 4096;
#pragma unroll
    for (int ni = 0; ni < 4; ni++)
#pragma unroll
        for (int r = 0; r < 4; r++)
            p[(wave * 16 + quad * 4 + r) * 64 + ni * 16 + l16] = acc[ni][r];
}

// softmax: grid (4, 64); block handles 16 d rows (wave*4 + r)
__global__ __launch_bounds__(256) void attn_softmax_kernel(
    const float* __restrict__ partial, bf16* __restrict__ attnb)
{
    int bh = blockIdx.y;
    int wave = threadIdx.x >> 6, lane = threadIdx.x & 63;
    for (int r = 0; r < 4; r++) {
        int d = blockIdx.x * 16 + wave * 4 + r;
        float v = 0.f;
#pragma unroll
        for (int s = 0; s < 8; s++) v += partial[((size_t)bh*8 + s)*4096 + d*64 + lane];
        v *= SCALE_;
        float m = v;
#pragma unroll
        for (int off = 32; off; off >>= 1) m = fmaxf(m, __shfl_xor(m, off));
        float p = expf(v - m);
        float sum = p;
#pragma unroll
        for (int off = 32; off; off >>= 1) sum += __shfl_xor(sum, off);
        attnb[(size_t)bh*4096 + d*64 + lane] = (bf16)(p / sum);
    }
}

// apply: outT[n][h*64+d] = sum_e attn[d][e] * q[n][h*64+e]
__global__ __launch_bounds__(256) void attn_apply_mfma(
    const bf16* __restrict__ q, const bf16* __restrict__ attnb,
    bf16* __restrict__ outT)
{
    int bh = blockIdx.y, b = bh >> 3, h = bh & 7;
    int t = threadIdx.x, wave = t >> 6, lane = t & 63;
    int quad = lane >> 4, l16 = lane & 15;
    int nbase = blockIdx.x * 256 + wave * 64;
    bf16x8 bfrag[4][2];
#pragma unroll
    for (int di = 0; di < 4; di++)
#pragma unroll
        for (int ks = 0; ks < 2; ks++)
            bfrag[di][ks] = *(const bf16x8*)&attnb[(size_t)bh*4096 + (di*16 + l16)*64 + ks*32 + quad*8];
    floatx4 acc[4][4] = {};
#pragma unroll
    for (int mi = 0; mi < 4; mi++) {
#pragma unroll
        for (int ks = 0; ks < 2; ks++) {
            bf16x8 af = *(const bf16x8*)&q[((size_t)b*N_ + nbase + mi*16 + l16)*512 + h*64 + ks*32 + quad*8];
#pragma unroll
            for (int di = 0; di < 4; di++)
                acc[mi][di] = __builtin_amdgcn_mfma_f32_16x16x32_bf16(af, bfrag[di][ks], acc[mi][di], 0, 0, 0);
        }
    }
#pragma unroll
    for (int mi = 0; mi < 4; mi++)
#pragma unroll
        for (int di = 0; di < 4; di++)
#pragma unroll
            for (int r = 0; r < 4; r++)
                outT[((size_t)b*N_ + nbase + mi*16 + quad*4 + r)*512 + h*64 + di*16 + l16] =
                    (bf16)acc[mi][di][r];
}

// ====================== ECA ================================================
__global__ __launch_bounds__(256) void pooled_kernel(
    const bf16* __restrict__ y, float* __restrict__ pooled)
{
    int bc = blockIdx.x;
    const bf16* p = y + (size_t)bc * 4096 + threadIdx.x * 16;
    float s = 0.f;
#pragma unroll
    for (int i = 0; i < 2; i++) {
        bf16x8 v = *(const bf16x8*)(p + i*8);
#pragma unroll
        for (int j = 0; j < 8; j++) s += (float)v[j];
    }
#pragma unroll
    for (int off = 32; off; off >>= 1) s += __shfl_xor(s, off);
    __shared__ float red[4];
    if ((threadIdx.x & 63) == 0) red[threadIdx.x >> 6] = s;
    __syncthreads();
    if (threadIdx.x == 0)
        pooled[bc] = (red[0] + red[1] + red[2] + red[3]) * (1.f/4096.f);
}

__global__ void gate_kernel(const float* __restrict__ pooled,
                            const bf16* __restrict__ eca_w, float* __restrict__ gate1)
{
    int c = threadIdx.x, b = blockIdx.x;
    float w0 = (float)eca_w[0], w1 = (float)eca_w[1], w2 = (float)eca_w[2];
    const float* p = pooled + b * 512;
    float conv = w1 * p[c];
    if (c > 0)   conv += w0 * p[c-1];
    if (c < 511) conv += w2 * p[c+1];
    float g = 1.f / (1.f + expf(-conv));
    gate1[b * 512 + c] = 1.f + g;
}

// ------- final, layout B: RMW fp32 d_out -------
__global__ __launch_bounds__(256) void final_rmw(
    const bf16* __restrict__ y, const float* __restrict__ gate1,
    float* __restrict__ out)
{
    int b = blockIdx.z, c0 = blockIdx.y * 64, n0 = blockIdx.x * 64;
    __shared__ float ytile[64][65];
    int t = threadIdx.x;
#pragma unroll
    for (int i = 0; i < 2; i++) {
        int chunk = t * 2 + i;
        int ci = chunk >> 3, nj = (chunk & 7) * 8;
        bf16x8 v = *(const bf16x8*)&y[(size_t)b * ((size_t)N_*C_) + (size_t)(c0+ci) * 4096 + n0 + nj];
#pragma unroll
        for (int j = 0; j < 8; j++) ytile[ci][nj+j] = (float)v[j];
    }
    __syncthreads();
    int cc = t & 63, nb = t >> 6;
    float g = gate1[b * 512 + c0 + cc];
    for (int p = 0; p < 16; p++) {
        int nr = p * 4 + nb;
        size_t idx = ((size_t)b * N_ + n0 + nr) * C_ + c0 + cc;
        out[idx] = out[idx] + g * ytile[cc][nr];
    }
}

// ------- final, layout A: read bf16 x2, write fresh fp32 -------
__global__ __launch_bounds__(256) void final_fresh(
    const bf16* __restrict__ y, const bf16* __restrict__ x2b,
    const float* __restrict__ gate1, float* __restrict__ out)
{
    int b = blockIdx.z, c0 = blockIdx.y * 64, n0 = blockIdx.x * 64;
    __shared__ float ytile[64][65];
    int t = threadIdx.x;
#pragma unroll
    for (int i = 0; i < 2; i++) {
        int chunk = t * 2 + i;
        int ci = chunk >> 3, nj = (chunk & 7) * 8;
        bf16x8 v = *(const bf16x8*)&y[(size_t)b * ((size_t)N_*C_) + (size_t)(c0+ci) * 4096 + n0 + nj];
#pragma unroll
        for (int j = 0; j < 8; j++) ytile[ci][nj+j] = (float)v[j];
    }
    __syncthreads();
    int cc = t & 63, nb = t >> 6;
    float g = gate1[b * 512 + c0 + cc];
    for (int p = 0; p < 16; p++) {
        int nr = p * 4 + nb;
        size_t idx = ((size_t)b * N_ + n0 + nr) * C_ + c0 + cc;
        out[idx] = (float)x2b[idx] + g * ytile[cc][nr];
    }
}

// ====================== launcher ===========================================
extern "C" void kernel_launch(void* const* d_in, const int* in_sizes, int n_in,
                              void* d_out, int out_size, void* d_ws, size_t ws_size,
                              hipStream_t stream)
{
    float* outf = (float*)d_out;
    bf16*  outb = (bf16*)d_out;
    char* ws = (char*)d_ws;

    int*   flag    = (int*)ws;
    float* pooled  = (float*)(ws + 4096);
    float* gate1   = (float*)(ws + 20480);
    bf16* ln1_w = (bf16*)(ws + 65536);
    bf16* ln1_b = (bf16*)(ws + 67584);
    bf16* ln2_w = (bf16*)(ws + 69632);
    bf16* ln2_b = (bf16*)(ws + 71680);
    bf16* proj_b= (bf16*)(ws + 73728);
    bf16* fc2_b = (bf16*)(ws + 75776);
    bf16* eca_w = (bf16*)(ws + 77824);
    bf16* fc1_b = (bf16*)(ws + 81920);
    bf16* qkv_w = (bf16*)(ws + ((size_t)1 << 20));
    bf16* proj_w= (bf16*)(ws + (size_t)2621440);
    bf16* fc1_w = (bf16*)(ws + ((size_t)3 << 20));
    bf16* fc2_w = (bf16*)(ws + ((size_t)5 << 20));
    float* partial = (float*)(ws + ((size_t)7  << 20));
    bf16*  attnb   = (bf16*)(ws + ((size_t)15 << 20));
    bf16*  T1      = (bf16*)(ws + ((size_t)16 << 20));
    bf16*  kvbuf   = (bf16*)(ws + ((size_t)48 << 20));
    bf16*  hbuf    = kvbuf;
    bf16*  x2b     = (bf16*)(ws + ((size_t)176 << 20));

    const bool fat = ws_size >= ((size_t)212 << 20);

    // 0. sniff input dtype
    sniff_kernel<<<1, 256, 0, stream>>>((const unsigned int*)d_in[0], flag);

    // 1. convert params to bf16
    ConvArgs ca;
    const int   srcidx[12] = { 1, 2, 6, 7, 5, 11, 12, 9, 3, 4, 8, 10 };
    const unsigned offs[12] = { 65536, 67584, 69632, 71680, 73728, 75776, 77824, 81920,
                                1u<<20, 2621440u, 3u<<20, 5u<<20 };
    for (int i = 0; i < 12; i++) {
        ca.src[i] = d_in[srcidx[i]];
        ca.dstoff[i] = offs[i];
        ca.n[i] = in_sizes[srcidx[i]];
    }
    convert_params<<<dim3(512, 12), 256, 0, stream>>>(ca, ws, flag);

    // 2. LN1 -> T1
    ln_dyn_kernel<<<BN_/4, 256, 0, stream>>>(d_in[0], ln1_w, ln1_b, T1, flag);

    // 3. QKV GEMM: q (bf16) -> d_out, kv -> kvbuf   (Mt=256, Nt=12)
    gemm128<bf16, EPI_QKV><<<3072, 256, 0, stream>>>(
        T1, qkv_w, nullptr, nullptr, flag, outb, kvbuf, BN_, 1536, 512);

    // 4. attention
    attn_logits_mfma<<<dim3(8, 64), 256, 0, stream>>>(kvbuf, partial);
    attn_softmax_kernel<<<dim3(4, 64), 256, 0, stream>>>(partial, attnb);
    attn_apply_mfma<<<dim3(16, 64), 256, 0, stream>>>(outb, attnb, T1);

    if (fat) {
        // 5. proj + bias + residual(x) -> x2b (bf16)
        gemm128<bf16, EPI_BIAS_RESID><<<1024, 256, 0, stream>>>(
            T1, proj_w, proj_b, d_in[0], flag, x2b, nullptr, BN_, 512, 512);
        // 6. LN2: x2b -> T1
        ln_b16_kernel<<<BN_/4, 256, 0, stream>>>(x2b, ln2_w, ln2_b, T1);
        // 7. FC1 full: T1 -> hbuf (128MB)   (Mt=256, Nt=16)
        gemm128<bf16, EPI_BIAS_GELU><<<4096, 256, 0, stream>>>(
            T1, fc1_w, fc1_b, nullptr, flag, hbuf, nullptr, BN_, 2048, 512);
        // 8. FC2 full: hbuf -> T1 (y)       (Mt=256, Nt=4)
        gemm128<bf16, EPI_BIAS><<<1024, 256, 0, stream>>>(
            hbuf, fc2_w, fc2_b, nullptr, flag, T1, nullptr, BN_, 512, 2048);
        // 9. ECA
        pooled_kernel<<<4096, 256, 0, stream>>>(T1, pooled);
        gate_kernel<<<8, 512, 0, stream>>>(pooled, eca_w, gate1);
        // 10. final: fp32 out = x2b + gate*y  (no RMW)
        final_fresh<<<dim3(64, 8, 8), 256, 0, stream>>>(T1, x2b, gate1, outf);
    } else {
        // 5. proj + bias + residual(x) -> x2 (fp32) in d_out
        gemm128<float, EPI_BIAS_RESID><<<1024, 256, 0, stream>>>(
            T1, proj_w, proj_b, d_in[0], flag, outf, nullptr, BN_, 512, 512);
        // 6. LN2: d_out fp32 -> T1
        ln_f32_kernel<<<BN_/4, 256, 0, stream>>>(outf, ln2_w, ln2_b, T1);
        // 7-8. chunked FC (hbuf 64MB)
        for (int ch = 0; ch < 2; ch++) {
            bf16* Tch = T1 + (size_t)ch * 16384 * 512;
            gemm128<bf16, EPI_BIAS_GELU><<<2048, 256, 0, stream>>>(
                Tch, fc1_w, fc1_b, nullptr, flag, hbuf, nullptr, 16384, 2048, 512);
            gemm128<bf16, EPI_BIAS><<<512, 256, 0, stream>>>(
                hbuf, fc2_w, fc2_b, nullptr, flag, Tch, nullptr, 16384, 512, 2048);
        }
        // 9. ECA
        pooled_kernel<<<4096, 256, 0, stream>>>(T1, pooled);
        gate_kernel<<<8, 512, 0, stream>>>(pooled, eca_w, gate1);
        // 10. final RMW on fp32 d_out
        final_rmw<<<dim3(64, 8, 8), 256, 0, stream>>>(T1, gate1, outf);
    }
}